// Round 10
// baseline (439.435 us; speedup 1.0000x reference)
//
#include <hip/hip_runtime.h>
#include <hip/hip_bf16.h>

// Problem constants: B,N,M,HID,NH = 16,512,1024,512,8; HS=64
#define BB 16
#define NN 512
#define MM 1024
#define HIDD 512
#define NHH 8

typedef unsigned short ushort_t;
typedef __attribute__((ext_vector_type(8))) short short8;      // 8 bf16
typedef __attribute__((ext_vector_type(8))) _Float16 half8;    // 8 fp16
typedef __attribute__((ext_vector_type(4))) _Float16 half4;
typedef __attribute__((ext_vector_type(4))) float f32x4;

__device__ __forceinline__ ushort_t f2bf(float x) {   // RNE fp32->bf16
    unsigned u = __float_as_uint(x);
    u += 0x7fff + ((u >> 16) & 1);
    return (ushort_t)(u >> 16);
}

// async global->LDS, 16B per lane (GEMM staging; layout contiguous per wave)
#define GLD16(g, l) __builtin_amdgcn_global_load_lds(                      \
    (const __attribute__((address_space(1))) void*)(g),                    \
    (__attribute__((address_space(3))) void*)(l), 16, 0, 0)

// XCD-aware swizzle: consecutive linear block ids land on XCD id%8.
__device__ __forceinline__ void xcd_swizzle(int& colb, int& rowb) {
    int id = blockIdx.x + blockIdx.y * gridDim.x;
    int C = gridDim.x;
    int xcd = id & 7;
    int slot = id >> 3;
    int rows_per = gridDim.y >> 3;
    colb = slot % C;
    rowb = xcd * rows_per + slot / C;
}

// ---------------------------------------------------------------------------
// bf16 MFMA GEMM, tile 128x128, BK=32, 4 waves (2x2 of 64x64). Double-buffered.
// ---------------------------------------------------------------------------
__global__ __launch_bounds__(256)
void gemm_bf(const ushort_t* __restrict__ A, const ushort_t* __restrict__ W,
             const float* __restrict__ bias, float* __restrict__ C,
             ushort_t* __restrict__ Cb, _Float16* __restrict__ Ch,
             int K, int Cout, int relu) {
    __shared__ __align__(16) ushort_t smem[2][8192];
    const int tid = threadIdx.x;
    const int lane = tid & 63;
    const int wid = tid >> 6;
    const int wm = wid >> 1, wn = wid & 1;
    int colb, rowb;
    xcd_swizzle(colb, rowb);
    const long row0 = (long)rowb * 128;
    const long col0 = (long)colb * 128;

    const int sr = lane >> 2;
    const int skq = lane & 3;
    const ushort_t* Ag = A + (row0 + wid * 32 + sr) * (long)K + skq * 8;
    const ushort_t* Wg = W + (col0 + wid * 32 + sr) * (long)K + skq * 8;
    const int sa0 = (wid * 32) * 32, sa1 = (wid * 32 + 16) * 32;

    f32x4 acc[4][4] = {};
    const int lr = lane & 15;
    const int kg = lane >> 4;

    GLD16(Ag, &smem[0][sa0]);
    GLD16(Ag + 16 * (long)K, &smem[0][sa1]);
    GLD16(Wg, &smem[0][4096 + sa0]);
    GLD16(Wg + 16 * (long)K, &smem[0][4096 + sa1]);

    int pb = 0;
    for (int k0 = 0; k0 < K; k0 += 32, pb ^= 1) {
        __syncthreads();
        int kn = k0 + 32;
        if (kn < K) {
            GLD16(Ag + kn, &smem[pb ^ 1][sa0]);
            GLD16(Ag + 16 * (long)K + kn, &smem[pb ^ 1][sa1]);
            GLD16(Wg + kn, &smem[pb ^ 1][4096 + sa0]);
            GLD16(Wg + 16 * (long)K + kn, &smem[pb ^ 1][4096 + sa1]);
        }
        const ushort_t* Ab = smem[pb];
        const ushort_t* Wb = smem[pb] + 4096;
        short8 af[4], bfr[4];
#pragma unroll
        for (int i = 0; i < 4; i++)
            af[i] = *(const short8*)&Ab[(wm * 64 + i * 16 + lr) * 32 + kg * 8];
#pragma unroll
        for (int j = 0; j < 4; j++)
            bfr[j] = *(const short8*)&Wb[(wn * 64 + j * 16 + lr) * 32 + kg * 8];
#pragma unroll
        for (int i = 0; i < 4; i++)
#pragma unroll
            for (int j = 0; j < 4; j++)
                acc[i][j] = __builtin_amdgcn_mfma_f32_16x16x32_bf16(
                    af[i], bfr[j], acc[i][j], 0, 0, 0);
    }

#pragma unroll
    for (int i = 0; i < 4; i++) {
#pragma unroll
        for (int j = 0; j < 4; j++) {
            long row = row0 + wm * 64 + i * 16 + kg * 4;
            long col = col0 + wn * 64 + j * 16 + lr;
            float bv = bias ? bias[col] : 0.f;
#pragma unroll
            for (int r = 0; r < 4; r++) {
                float x = acc[i][j][r] + bv;
                if (relu) x = fmaxf(x, 0.f);
                size_t idx = (row + r) * (size_t)Cout + col;
                if (Ch)      Ch[idx] = (_Float16)x;
                else if (Cb) Cb[idx] = f2bf(x);
                else         C[idx] = x;
            }
        }
    }
}

// ---------------------------------------------------------------------------
// bf16 MFMA GEMM, tile 128x64, BK=32, 4 waves, each 32x64. Double-buffered.
// ---------------------------------------------------------------------------
__global__ __launch_bounds__(256)
void gemm_bf64(const ushort_t* __restrict__ A, const ushort_t* __restrict__ W,
               const float* __restrict__ bias, float* __restrict__ C,
               ushort_t* __restrict__ Cb, _Float16* __restrict__ Ch,
               int K, int Cout, int relu) {
    __shared__ __align__(16) ushort_t smem[2][6144];
    const int tid = threadIdx.x;
    const int lane = tid & 63;
    const int w = tid >> 6;
    int colb, rowb;
    xcd_swizzle(colb, rowb);
    const long row0 = (long)rowb * 128;
    const long col0 = (long)colb * 64;

    const int sr = lane >> 2;
    const int skq = lane & 3;
    const ushort_t* Ag = A + (row0 + w * 32 + sr) * (long)K + skq * 8;
    const ushort_t* Wg = W + (col0 + w * 16 + sr) * (long)K + skq * 8;
    const int sa0 = (w * 32) * 32, sa1 = (w * 32 + 16) * 32;
    const int sw0 = 4096 + (w * 16) * 32;

    f32x4 acc[2][4] = {};
    const int lr = lane & 15;
    const int kg = lane >> 4;

    GLD16(Ag, &smem[0][sa0]);
    GLD16(Ag + 16 * (long)K, &smem[0][sa1]);
    GLD16(Wg, &smem[0][sw0]);

    int pb = 0;
    for (int k0 = 0; k0 < K; k0 += 32, pb ^= 1) {
        __syncthreads();
        int kn = k0 + 32;
        if (kn < K) {
            GLD16(Ag + kn, &smem[pb ^ 1][sa0]);
            GLD16(Ag + 16 * (long)K + kn, &smem[pb ^ 1][sa1]);
            GLD16(Wg + kn, &smem[pb ^ 1][sw0]);
        }
        const ushort_t* Ab = smem[pb];
        const ushort_t* Wb = smem[pb] + 4096;
        short8 af[2], bfr[4];
#pragma unroll
        for (int i = 0; i < 2; i++)
            af[i] = *(const short8*)&Ab[(w * 32 + i * 16 + lr) * 32 + kg * 8];
#pragma unroll
        for (int j = 0; j < 4; j++)
            bfr[j] = *(const short8*)&Wb[(j * 16 + lr) * 32 + kg * 8];
#pragma unroll
        for (int i = 0; i < 2; i++)
#pragma unroll
            for (int j = 0; j < 4; j++)
                acc[i][j] = __builtin_amdgcn_mfma_f32_16x16x32_bf16(
                    af[i], bfr[j], acc[i][j], 0, 0, 0);
    }

#pragma unroll
    for (int i = 0; i < 2; i++) {
#pragma unroll
        for (int j = 0; j < 4; j++) {
            long row = row0 + w * 32 + i * 16 + kg * 4;
            long col = col0 + j * 16 + lr;
            float bv = bias ? bias[col] : 0.f;
#pragma unroll
            for (int r = 0; r < 4; r++) {
                float x = acc[i][j][r] + bv;
                if (relu) x = fmaxf(x, 0.f);
                size_t idx = (row + r) * (size_t)Cout + col;
                if (Ch)      Ch[idx] = (_Float16)x;
                else if (Cb) Cb[idx] = f2bf(x);
                else         C[idx] = x;
            }
        }
    }
}

// ---------------------------------------------------------------------------
// gemm_q_rot: 128x64-tile GEMM (Cout=512, K=512), col-block = one head.
// Double-buffered; epilogue Cs overlays staging LDS; rotates -> Qrot f16.
// ---------------------------------------------------------------------------
__global__ __launch_bounds__(256)
void gemm_q_rot(const ushort_t* __restrict__ A, const ushort_t* __restrict__ W,
                const float* __restrict__ bias,
                const float* __restrict__ sn, const float* __restrict__ cs,
                _Float16* __restrict__ Qrot) {
    __shared__ __align__(16) ushort_t smem[2][6144];
    _Float16* Cs = (_Float16*)smem;
    const int K = 512;
    const int tid = threadIdx.x;
    const int lane = tid & 63;
    const int w = tid >> 6;
    int colb, rowb;
    xcd_swizzle(colb, rowb);
    const long row0 = (long)rowb * 128;
    const int h = colb;
    const long col0 = (long)h * 64;

    const int sr = lane >> 2;
    const int skq = lane & 3;
    const ushort_t* Ag = A + (row0 + w * 32 + sr) * (long)K + skq * 8;
    const ushort_t* Wg = W + (col0 + w * 16 + sr) * (long)K + skq * 8;
    const int sa0 = (w * 32) * 32, sa1 = (w * 32 + 16) * 32;
    const int sw0 = 4096 + (w * 16) * 32;

    f32x4 acc[2][4] = {};
    const int lr = lane & 15;
    const int kg = lane >> 4;

    GLD16(Ag, &smem[0][sa0]);
    GLD16(Ag + 16 * (long)K, &smem[0][sa1]);
    GLD16(Wg, &smem[0][sw0]);

    int pb = 0;
    for (int k0 = 0; k0 < K; k0 += 32, pb ^= 1) {
        __syncthreads();
        int kn = k0 + 32;
        if (kn < K) {
            GLD16(Ag + kn, &smem[pb ^ 1][sa0]);
            GLD16(Ag + 16 * (long)K + kn, &smem[pb ^ 1][sa1]);
            GLD16(Wg + kn, &smem[pb ^ 1][sw0]);
        }
        const ushort_t* Ab = smem[pb];
        const ushort_t* Wb = smem[pb] + 4096;
        short8 af[2], bfr[4];
#pragma unroll
        for (int i = 0; i < 2; i++)
            af[i] = *(const short8*)&Ab[(w * 32 + i * 16 + lr) * 32 + kg * 8];
#pragma unroll
        for (int j = 0; j < 4; j++)
            bfr[j] = *(const short8*)&Wb[(j * 16 + lr) * 32 + kg * 8];
#pragma unroll
        for (int i = 0; i < 2; i++)
#pragma unroll
            for (int j = 0; j < 4; j++)
                acc[i][j] = __builtin_amdgcn_mfma_f32_16x16x32_bf16(
                    af[i], bfr[j], acc[i][j], 0, 0, 0);
    }

    __syncthreads();
#pragma unroll
    for (int i = 0; i < 2; i++)
#pragma unroll
        for (int j = 0; j < 4; j++) {
            int row = w * 32 + i * 16 + kg * 4;
            int col = j * 16 + lr;
            float bv = bias[col0 + col];
#pragma unroll
            for (int r = 0; r < 4; r++)
                Cs[(row + r) * 76 + col] = (_Float16)(acc[i][j][r] + bv);
        }
    __syncthreads();
    for (int idx = tid; idx < 4096; idx += 256) {
        int rr = idx >> 5, j = idx & 31;
        size_t srow = (size_t)row0 + rr;
        float x0 = (float)Cs[rr * 76 + 2 * j], x1 = (float)Cs[rr * 76 + 2 * j + 1];
        float s = sn[srow * 32 + j], c = cs[srow * 32 + j];
        Qrot[srow * 512 + h * 64 + j]      = (_Float16)(x0 * c - x1 * s);
        Qrot[srow * 512 + h * 64 + 32 + j] = (_Float16)(x1 * c + x0 * s);
    }
}

// ---------------------------------------------------------------------------
// gemm_kv: 128x128-tile GEMM (Cout=1024, K=512), col-block = one head's k|v.
// Double-buffered; epilogue: rotate k -> Krot, transpose v -> Vth.
// ---------------------------------------------------------------------------
__global__ __launch_bounds__(256)
void gemm_kv(const ushort_t* __restrict__ A, const ushort_t* __restrict__ W,
             const float* __restrict__ bias,
             const float* __restrict__ sn, const float* __restrict__ cs,
             _Float16* __restrict__ Krot, _Float16* __restrict__ Vth) {
    __shared__ __align__(16) ushort_t smem[2][8192];
    _Float16* Cs = (_Float16*)smem;
    const int K = 512;
    const int tid = threadIdx.x;
    const int lane = tid & 63;
    const int wid = tid >> 6;
    const int wm = wid >> 1, wn = wid & 1;
    int colb, rowb;
    xcd_swizzle(colb, rowb);
    const long row0 = (long)rowb * 128;
    const int h = colb;
    const long col0 = (long)h * 128;

    const int sr = lane >> 2;
    const int skq = lane & 3;
    const ushort_t* Ag = A + (row0 + wid * 32 + sr) * (long)K + skq * 8;
    const ushort_t* Wg = W + (col0 + wid * 32 + sr) * (long)K + skq * 8;
    const int sa0 = (wid * 32) * 32, sa1 = (wid * 32 + 16) * 32;

    f32x4 acc[4][4] = {};
    const int lr = lane & 15;
    const int kg = lane >> 4;

    GLD16(Ag, &smem[0][sa0]);
    GLD16(Ag + 16 * (long)K, &smem[0][sa1]);
    GLD16(Wg, &smem[0][4096 + sa0]);
    GLD16(Wg + 16 * (long)K, &smem[0][4096 + sa1]);

    int pb = 0;
    for (int k0 = 0; k0 < K; k0 += 32, pb ^= 1) {
        __syncthreads();
        int kn = k0 + 32;
        if (kn < K) {
            GLD16(Ag + kn, &smem[pb ^ 1][sa0]);
            GLD16(Ag + 16 * (long)K + kn, &smem[pb ^ 1][sa1]);
            GLD16(Wg + kn, &smem[pb ^ 1][4096 + sa0]);
            GLD16(Wg + 16 * (long)K + kn, &smem[pb ^ 1][4096 + sa1]);
        }
        const ushort_t* Ab = smem[pb];
        const ushort_t* Wb = smem[pb] + 4096;
        short8 af[4], bfr[4];
#pragma unroll
        for (int i = 0; i < 4; i++)
            af[i] = *(const short8*)&Ab[(wm * 64 + i * 16 + lr) * 32 + kg * 8];
#pragma unroll
        for (int j = 0; j < 4; j++)
            bfr[j] = *(const short8*)&Wb[(wn * 64 + j * 16 + lr) * 32 + kg * 8];
#pragma unroll
        for (int i = 0; i < 4; i++)
#pragma unroll
            for (int j = 0; j < 4; j++)
                acc[i][j] = __builtin_amdgcn_mfma_f32_16x16x32_bf16(
                    af[i], bfr[j], acc[i][j], 0, 0, 0);
    }

    const int b_ = (int)(row0 >> 10);
    const int m0_ = (int)(row0 & 1023);
#pragma unroll
    for (int half = 0; half < 2; half++) {
        __syncthreads();
        if (wn == half) {
#pragma unroll
            for (int i = 0; i < 4; i++)
#pragma unroll
                for (int j = 0; j < 4; j++) {
                    int row = wm * 64 + i * 16 + kg * 4;
                    int col = j * 16 + lr;
                    float bv = bias[col0 + half * 64 + col];
#pragma unroll
                    for (int r = 0; r < 4; r++)
                        Cs[(row + r) * 76 + col] = (_Float16)(acc[i][j][r] + bv);
                }
        }
        __syncthreads();
        if (half == 0) {
            for (int idx = tid; idx < 4096; idx += 256) {
                int rr = idx >> 5, j = idx & 31;
                size_t srow = (size_t)row0 + rr;
                float x0 = (float)Cs[rr * 76 + 2 * j], x1 = (float)Cs[rr * 76 + 2 * j + 1];
                float s = sn[srow * 32 + j], c = cs[srow * 32 + j];
                Krot[srow * 512 + h * 64 + j]      = (_Float16)(x0 * c - x1 * s);
                Krot[srow * 512 + h * 64 + 32 + j] = (_Float16)(x1 * c + x0 * s);
            }
        } else {
            for (int idx = tid; idx < 1024; idx += 256) {
                int d = idx >> 4, c = idx & 15;
                half8 v;
#pragma unroll
                for (int k = 0; k < 8; k++) v[k] = Cs[(c * 8 + k) * 76 + d];
                *(half8*)(Vth + (((size_t)(b_ * NHH + h)) * 64 + d) * MM
                          + m0_ + c * 8) = v;
            }
        }
    }
}

// ---------------------------------------------------------------------------
// One-shot fp32->bf16 convert of tgt, mem, and all 7 weight mats.
// ---------------------------------------------------------------------------
__global__ __launch_bounds__(256)
void cvt_all(const float* __restrict__ tgt, const float* __restrict__ mem,
             const float* __restrict__ w0, const float* __restrict__ w1,
             const float* __restrict__ w2, const float* __restrict__ w3,
             const float* __restrict__ w4, const float* __restrict__ w5,
             const float* __restrict__ w6,
             ushort_t* __restrict__ Abf, ushort_t* __restrict__ membf,
             ushort_t* __restrict__ Wbf) {
    int blk = blockIdx.x;
    const float* src;
    ushort_t* dst;
    size_t off;
    if (blk < 4096)       { src = tgt; dst = Abf;   off = (size_t)blk * 1024; }
    else if (blk < 12288) { src = mem; dst = membf; off = (size_t)(blk - 4096) * 1024; }
    else {
        int wb = blk - 12288;
        dst = Wbf + (size_t)wb * 1024;
        if (wb < 768)       { src = w0; off = (size_t)wb * 1024; }
        else if (wb < 1024) { src = w1; off = (size_t)(wb - 768) * 1024; }
        else if (wb < 1280) { src = w2; off = (size_t)(wb - 1024) * 1024; }
        else if (wb < 1792) { src = w3; off = (size_t)(wb - 1280) * 1024; }
        else if (wb < 2048) { src = w4; off = (size_t)(wb - 1792) * 1024; }
        else if (wb < 3072) { src = w5; off = (size_t)(wb - 2048) * 1024; }
        else                { src = w6; off = (size_t)(wb - 3072) * 1024; }
        float4 v = *(const float4*)(src + off + threadIdx.x * 4);
        ushort4 o;
        o.x = f2bf(v.x); o.y = f2bf(v.y); o.z = f2bf(v.z); o.w = f2bf(v.w);
        *(ushort4*)(dst + threadIdx.x * 4) = o;
        return;
    }
    float4 v = *(const float4*)(src + off + threadIdx.x * 4);
    ushort4 o;
    o.x = f2bf(v.x); o.y = f2bf(v.y); o.z = f2bf(v.z); o.w = f2bf(v.w);
    *(ushort4*)(dst + off + threadIdx.x * 4) = o;
}

// ---------------------------------------------------------------------------
// prep_vt: transpose 64-wide V slice per head (self-attention path).
// ---------------------------------------------------------------------------
__global__ __launch_bounds__(256)
void prep_vt(const _Float16* __restrict__ src, int L, int stride,
             int hmul, int hadd, _Float16* __restrict__ Vt) {
    const int b = blockIdx.z, h = blockIdx.y, m0 = blockIdx.x * 64;
    const int tid = threadIdx.x;
    __shared__ _Float16 vt[64][72];
    for (int idx = tid; idx < 512; idx += 256) {
        int m = idx >> 3, c = idx & 7;
        half8 v = *(const half8*)(src + ((size_t)(b * L + m0 + m)) * stride
                                  + h * hmul + hadd + c * 8);
#pragma unroll
        for (int k = 0; k < 8; k++) vt[c * 8 + k][m] = v[k];
    }
    __syncthreads();
    for (int idx = tid; idx < 512; idx += 256) {
        int d = idx >> 3, c = idx & 7;
        *(half8*)(Vt + (((size_t)(b * NHH + h)) * 64 + d) * L + m0 + c * 8)
            = *(const half8*)&vt[d][c * 8];
    }
}

// ---------------------------------------------------------------------------
// Flash MFMA attention v4: attn2's partition (4 waves x 32 q = 128 q/block,
// grid 512 -> good K/V staging amortization) + stride-76 LDS (gcd(38,32)=2,
// conflict-free - verified R9) + exp2-folded softmax.
// ---------------------------------------------------------------------------
__global__ __launch_bounds__(256)
void attn4(const _Float16* __restrict__ Q, int qstride, int qmul, int qadd,
           const _Float16* __restrict__ K, int kstride, int kmul, int kadd,
           const _Float16* __restrict__ Vt, int LV, int Lrows,
           ushort_t* __restrict__ out, int kvlen, int causal) {
    const int g = blockIdx.x;
    const int bh = (g & 7) * 16 + ((g >> 3) & 15);
    const int qb = g >> 7;
    const int b = bh >> 3, h = bh & 7;
    const int n0 = qb * 128;
    const int tid = threadIdx.x, lane = tid & 63, w = tid >> 6;
    const int quad = lane >> 4, l16 = lane & 15;
    const int qw = n0 + w * 32;
    const float SC = 0.125f * 1.44269504089f;    // (1/sqrt(64)) * log2(e)

    __shared__ _Float16 Ks[64 * 76];
    __shared__ _Float16 Vs[64 * 76];
    __shared__ _Float16 Ps[4][32 * 76];
    _Float16* Pw = Ps[w];

    half8 bq[2][2];
#pragma unroll
    for (int s = 0; s < 2; s++)
#pragma unroll
        for (int c = 0; c < 2; c++)
            bq[s][c] = *(const half8*)(Q + ((size_t)(b * NN + qw + s * 16 + l16)) * qstride
                                       + h * qmul + qadd + c * 32 + quad * 8);

    f32x4 acc[2][4] = {};
    float mrun[2] = {-3e38f, -3e38f}, lrun[2] = {0.f, 0.f};

    const int srow = tid >> 3;
    const int scol = (tid & 7) * 8;
    const int limit = causal ? (n0 + 128) : kvlen;

    half8 kr0, kr1, vr0, vr1;
    {
        size_t kb = ((size_t)(b * Lrows + srow)) * kstride + h * kmul + kadd + scol;
        kr0 = *(const half8*)(K + kb);
        kr1 = *(const half8*)(K + kb + (size_t)32 * kstride);
        size_t vb = (((size_t)(b * NHH + h)) * 64 + srow) * (size_t)LV + scol;
        vr0 = *(const half8*)(Vt + vb);
        vr1 = *(const half8*)(Vt + vb + (size_t)32 * LV);
    }

    for (int key0 = 0; key0 < limit; key0 += 64) {
        __syncthreads();
        *(half8*)&Ks[srow * 76 + scol] = kr0;
        *(half8*)&Ks[(srow + 32) * 76 + scol] = kr1;
        *(half8*)&Vs[srow * 76 + scol] = vr0;
        *(half8*)&Vs[(srow + 32) * 76 + scol] = vr1;
        __syncthreads();
        int knext = key0 + 64;
        if (knext < limit) {
            size_t kb = ((size_t)(b * Lrows + knext + srow)) * kstride
                        + h * kmul + kadd + scol;
            kr0 = *(const half8*)(K + kb);
            kr1 = *(const half8*)(K + kb + (size_t)32 * kstride);
            size_t vb = (((size_t)(b * NHH + h)) * 64 + srow) * (size_t)LV
                        + knext + scol;
            vr0 = *(const half8*)(Vt + vb);
            vr1 = *(const half8*)(Vt + vb + (size_t)32 * LV);
        }
        if (causal && key0 > qw + 31) continue;

        f32x4 st[2][4];
#pragma unroll
        for (int kt = 0; kt < 4; kt++) {
            half8 ak0 = *(const half8*)&Ks[(kt * 16 + l16) * 76 + quad * 8];
            half8 ak1 = *(const half8*)&Ks[(kt * 16 + l16) * 76 + 32 + quad * 8];
#pragma unroll
            for (int s = 0; s < 2; s++) {
                f32x4 z = {};
                z = __builtin_amdgcn_mfma_f32_16x16x32_f16(ak0, bq[s][0], z, 0, 0, 0);
                z = __builtin_amdgcn_mfma_f32_16x16x32_f16(ak1, bq[s][1], z, 0, 0, 0);
                st[s][kt] = z;
            }
        }
        if (causal && key0 + 64 > qw) {
#pragma unroll
            for (int s = 0; s < 2; s++) {
                int qabs = qw + s * 16 + l16;
#pragma unroll
                for (int kt = 0; kt < 4; kt++)
#pragma unroll
                    for (int r = 0; r < 4; r++)
                        if (key0 + kt * 16 + quad * 4 + r > qabs)
                            st[s][kt][r] = -3e38f;
            }
        }
#pragma unroll
        for (int s = 0; s < 2; s++) {
            float lm = -3e38f;
#pragma unroll
            for (int kt = 0; kt < 4; kt++)
                lm = fmaxf(lm, fmaxf(fmaxf(st[s][kt][0], st[s][kt][1]),
                                     fmaxf(st[s][kt][2], st[s][kt][3])));
            lm = fmaxf(lm, __shfl_xor(lm, 16));
            lm = fmaxf(lm, __shfl_xor(lm, 32));
            float mnew = fmaxf(mrun[s], lm);
            float corr = exp2f((mrun[s] - mnew) * SC);
            mrun[s] = mnew;
            float ls = 0.f;
#pragma unroll
            for (int kt = 0; kt < 4; kt++) {
                half4 ph;
#pragma unroll
                for (int r = 0; r < 4; r++) {
                    float p = exp2f((st[s][kt][r] - mnew) * SC);
                    ls += p;
                    ph[r] = (_Float16)p;
                }
                *(half4*)&Pw[(s * 16 + l16) * 76 + kt * 16 + quad * 4] = ph;
            }
            ls += __shfl_xor(ls, 16);
            ls += __shfl_xor(ls, 32);
            lrun[s] = lrun[s] * corr + ls;
            float cb0 = __shfl(corr, (lane & 48) | (quad * 4 + 0));
            float cb1 = __shfl(corr, (lane & 48) | (quad * 4 + 1));
            float cb2 = __shfl(corr, (lane & 48) | (quad * 4 + 2));
            float cb3 = __shfl(corr, (lane & 48) | (quad * 4 + 3));
#pragma unroll
            for (int dt = 0; dt < 4; dt++) {
                acc[s][dt][0] *= cb0; acc[s][dt][1] *= cb1;
                acc[s][dt][2] *= cb2; acc[s][dt][3] *= cb3;
            }
        }
        half8 ap[2][2];
#pragma unroll
        for (int s = 0; s < 2; s++)
#pragma unroll
            for (int c = 0; c < 2; c++)
                ap[s][c] = *(const half8*)&Pw[(s * 16 + l16) * 76 + c * 32 + quad * 8];
#pragma unroll
        for (int dt = 0; dt < 4; dt++) {
            half8 bv0 = *(const half8*)&Vs[(dt * 16 + l16) * 76 + quad * 8];
            half8 bv1 = *(const half8*)&Vs[(dt * 16 + l16) * 76 + 32 + quad * 8];
#pragma unroll
            for (int s = 0; s < 2; s++) {
                acc[s][dt] = __builtin_amdgcn_mfma_f32_16x16x32_f16(ap[s][0], bv0, acc[s][dt], 0, 0, 0);
                acc[s][dt] = __builtin_amdgcn_mfma_f32_16x16x32_f16(ap[s][1], bv1, acc[s][dt], 0, 0, 0);
            }
        }
    }
#pragma unroll
    for (int s = 0; s < 2; s++) {
        float invq = 1.f / lrun[s];
        float iv0 = __shfl(invq, (lane & 48) | (quad * 4 + 0));
        float iv1 = __shfl(invq, (lane & 48) | (quad * 4 + 1));
        float iv2 = __shfl(invq, (lane & 48) | (quad * 4 + 2));
        float iv3 = __shfl(invq, (lane & 48) | (quad * 4 + 3));
#pragma unroll
        for (int dt = 0; dt < 4; dt++) {
            size_t base = ((size_t)(b * NN + qw + s * 16 + quad * 4)) * 512
                          + h * 64 + dt * 16 + l16;
            out[base]           = f2bf(acc[s][dt][0] * iv0);
            out[base + 512]     = f2bf(acc[s][dt][1] * iv1);
            out[base + 1024]    = f2bf(acc[s][dt][2] * iv2);
            out[base + 1536]    = f2bf(acc[s][dt][3] * iv3);
        }
    }
}

// ---------------------------------------------------------------------------
// out = LayerNorm(sum_{s<nsplit} u[s] + res)*g + beta; optional bf16 copy.
// ---------------------------------------------------------------------------
__global__ __launch_bounds__(256)
void ln_residual(const float* __restrict__ u, int nsplit,
                 const float* __restrict__ res,
                 const float* __restrict__ g, const float* __restrict__ be,
                 float* __restrict__ out, ushort_t* __restrict__ outbf) {
    const int row = blockIdx.x, t = threadIdx.x;
    const float* rp = res + (size_t)row * HIDD;
    float z0 = rp[t];
    float z1 = rp[t + 256];
    for (int s = 0; s < nsplit; s++) {
        const float* up = u + (size_t)s * 4194304 + (size_t)row * HIDD;
        z0 += up[t];
        z1 += up[t + 256];
    }
    float sm = z0 + z1, s2 = z0 * z0 + z1 * z1;
#pragma unroll
    for (int off = 1; off < 64; off <<= 1) {
        sm += __shfl_xor(sm, off, 64);
        s2 += __shfl_xor(s2, off, 64);
    }
    __shared__ float ps[4], ps2[4];
    int w = t >> 6;
    if ((t & 63) == 0) { ps[w] = sm; ps2[w] = s2; }
    __syncthreads();
    sm = ps[0] + ps[1] + ps[2] + ps[3];
    s2 = ps2[0] + ps2[1] + ps2[2] + ps2[3];
    float mu = sm * (1.f / 512.f);
    float var = s2 * (1.f / 512.f) - mu * mu;
    float rstd = rsqrtf(var + 1e-5f);
    float y0 = (z0 - mu) * rstd * g[t] + be[t];
    float y1 = (z1 - mu) * rstd * g[t + 256] + be[t + 256];
    out[(size_t)row * HIDD + t]       = y0;
    out[(size_t)row * HIDD + t + 256] = y1;
    if (outbf) {
        outbf[(size_t)row * HIDD + t]       = f2bf(y0);
        outbf[(size_t)row * HIDD + t + 256] = f2bf(y1);
    }
}

// ---------------------------------------------------------------------------
extern "C" void kernel_launch(void* const* d_in, const int* in_sizes, int n_in,
                              void* d_out, int out_size, void* d_ws, size_t ws_size,
                              hipStream_t stream) {
    const float* tgt      = (const float*)d_in[0];
    const float* mem      = (const float*)d_in[1];
    const float* pep_sin  = (const float*)d_in[2];
    const float* pep_cos  = (const float*)d_in[3];
    const float* pk_sin   = (const float*)d_in[4];
    const float* pk_cos   = (const float*)d_in[5];
    const float* mmha_w   = (const float*)d_in[8];
    const float* mmha_b   = (const float*)d_in[9];
    const float* mmha_ow  = (const float*)d_in[10];
    const float* mmha_ob  = (const float*)d_in[11];
    const float* mmha_g   = (const float*)d_in[12];
    const float* mmha_be  = (const float*)d_in[13];
    const float* mha_qw   = (const float*)d_in[14];
    const float* mha_qb   = (const float*)d_in[15];
    const float* mha_kvw  = (const float*)d_in[16];
    const float* mha_kvb  = (const float*)d_in[17];
    const float* mha_ow   = (const float*)d_in[18];
    const float* mha_ob   = (const float*)d_in[19];
    const float* mha_g    = (const float*)d_in[20];
    const float* mha_be   = (const float*)d_in[21];
    const float* ffn_w1   = (const float*)d_in[22];
    const float* ffn_w2   = (const float*)d_in[23];
    const float* ffn_g    = (const float*)d_in[24];
    const float* ffn_be   = (const float*)d_in[25];

    float* ws = (float*)d_ws;
    float* utmp  = ws;                        //  4,194,304 f32
    float* tgt12 = ws + 4194304;              //  4,194,304 f32
    _Float16* hp = (_Float16*)(ws + 8388608); // half pool (offsets in halves)
    _Float16* qkvh  = hp;                     // 12,582,912 (B*N*1536)
    _Float16* Qrot  = hp + 12582912;          //  4,194,304
    _Float16* Vth   = hp + 16777216;          //  8,388,608 (self uses half)
    _Float16* Krot  = hp + 25165824;          //  8,388,608
    ushort_t* membf = (ushort_t*)(hp + 33554432); // 8,388,608 bf16
    ushort_t* Abf   = (ushort_t*)(hp + 41943040); // 4,194,304 bf16
    ushort_t* Wbf   = (ushort_t*)(hp + 46137344); // 4,194,304 bf16 weights
    ushort_t* w_mmha = Wbf;                   //   786,432
    ushort_t* w_mmow = Wbf + 786432;          //   262,144
    ushort_t* w_qw   = Wbf + 1048576;         //   262,144
    ushort_t* w_kvw  = Wbf + 1310720;         //   524,288
    ushort_t* w_mow  = Wbf + 1835008;         //   262,144
    ushort_t* w_f1   = Wbf + 2097152;         // 1,048,576
    ushort_t* w_f2   = Wbf + 3145728;         // 1,048,576
    ushort_t* hbf = (ushort_t*)qkvh;          // ffn hidden bf16 spans qkvh+Qrot
    float* out = (float*)d_out;
    (void)in_sizes; (void)n_in; (void)out_size; (void)ws_size;

    // 0. all fp32->bf16 converts in one launch
    cvt_all<<<16384, 256, 0, stream>>>(tgt, mem, mmha_w, mmha_ow, mha_qw,
                                       mha_kvw, mha_ow, ffn_w1, ffn_w2,
                                       Abf, membf, Wbf);
    // 1. qkv = tgt @ mmha_w.T + b  (8192x512x1536, f16 out)
    gemm_bf<<<dim3(12, 64), 256, 0, stream>>>(Abf, w_mmha, mmha_b, nullptr, nullptr, qkvh, 512, 1536, 0);
    // 2. self-attention (causal), 128 q/block
    prep_vt<<<dim3(8, NHH, BB), 256, 0, stream>>>(qkvh, NN, 1536, 192, 128, Vth);
    attn4<<<512, 256, 0, stream>>>(qkvh, 1536, 192, 0, qkvh, 1536, 192, 64,
                                   Vth, NN, NN, Abf, 0, 1);
    // 3. tgt1 = LN(x @ ow.T + ob + tgt)
    gemm_bf64<<<dim3(8, 64), 256, 0, stream>>>(Abf, w_mmow, mmha_ob, utmp, nullptr, nullptr, 512, 512, 0);
    ln_residual<<<8192, 256, 0, stream>>>(utmp, 1, tgt, mmha_g, mmha_be, tgt12, Abf);
    // 4. Qrot = rot(tgt1 @ qw.T + qb)
    gemm_q_rot<<<dim3(8, 64), 256, 0, stream>>>(Abf, w_qw, mha_qb, pep_sin, pep_cos, Qrot);
    // 5. kv GEMM with fused k-rotation + v-transpose epilogue
    gemm_kv<<<dim3(8, 128), 256, 0, stream>>>(membf, w_kvw, mha_kvb, pk_sin, pk_cos, Krot, Vth);
    // 6. cross-attention (960 valid keys), 128 q/block
    attn4<<<512, 256, 0, stream>>>(Qrot, 512, 64, 0, Krot, 512, 64, 0,
                                   Vth, MM, MM, Abf, MM - 64, 0);
    // 7. tgt2 = LN(x2 @ ow.T + ob + tgt1)
    gemm_bf64<<<dim3(8, 64), 256, 0, stream>>>(Abf, w_mow, mha_ob, utmp, nullptr, nullptr, 512, 512, 0);
    ln_residual<<<8192, 256, 0, stream>>>(utmp, 1, tgt12, mha_g, mha_be, tgt12, Abf);
    // 8. h = relu(tgt2 @ w1.T)     (8192x512x2048, bf16 out)
    gemm_bf<<<dim3(16, 64), 256, 0, stream>>>(Abf, w_f1, nullptr, nullptr, hbf, nullptr, 512, 2048, 1);
    // 9. h2 = h @ w2.T  (8192x2048x512) 128x64 tiles, full K, XCD-swizzled
    gemm_bf64<<<dim3(8, 64), 256, 0, stream>>>(hbf, w_f2, nullptr, utmp, nullptr, nullptr, 2048, 512, 0);
    // 10. out = LN(tgt2 + h2)
    ln_residual<<<8192, 256, 0, stream>>>(utmp, 1, tgt12, ffn_g, ffn_be, out, nullptr);
}

// Round 12
// 417.661 us; speedup vs baseline: 1.0521x; 1.0521x over previous
//
#include <hip/hip_runtime.h>
#include <hip/hip_bf16.h>

// Problem constants: B,N,M,HID,NH = 16,512,1024,512,8; HS=64
#define BB 16
#define NN 512
#define MM 1024
#define HIDD 512
#define NHH 8

typedef unsigned short ushort_t;
typedef __attribute__((ext_vector_type(8))) short short8;      // 8 bf16
typedef __attribute__((ext_vector_type(8))) _Float16 half8;    // 8 fp16
typedef __attribute__((ext_vector_type(4))) _Float16 half4;
typedef __attribute__((ext_vector_type(4))) float f32x4;

__device__ __forceinline__ ushort_t f2bf(float x) {   // RNE fp32->bf16
    unsigned u = __float_as_uint(x);
    u += 0x7fff + ((u >> 16) & 1);
    return (ushort_t)(u >> 16);
}

// async global->LDS, 16B per lane (GEMM staging; layout contiguous per wave)
#define GLD16(g, l) __builtin_amdgcn_global_load_lds(                      \
    (const __attribute__((address_space(1))) void*)(g),                    \
    (__attribute__((address_space(3))) void*)(l), 16, 0, 0)

// XCD-aware swizzle: consecutive linear block ids land on XCD id%8.
__device__ __forceinline__ void xcd_swizzle(int& colb, int& rowb) {
    int id = blockIdx.x + blockIdx.y * gridDim.x;
    int C = gridDim.x;
    int xcd = id & 7;
    int slot = id >> 3;
    int rows_per = gridDim.y >> 3;
    colb = slot % C;
    rowb = xcd * rows_per + slot / C;
}

// ---------------------------------------------------------------------------
// bf16 MFMA GEMM, tile 128x128, BK=32, 4 waves (2x2 of 64x64). Double-buffered.
// ---------------------------------------------------------------------------
__global__ __launch_bounds__(256)
void gemm_bf(const ushort_t* __restrict__ A, const ushort_t* __restrict__ W,
             const float* __restrict__ bias, float* __restrict__ C,
             ushort_t* __restrict__ Cb, _Float16* __restrict__ Ch,
             int K, int Cout, int relu) {
    __shared__ __align__(16) ushort_t smem[2][8192];
    const int tid = threadIdx.x;
    const int lane = tid & 63;
    const int wid = tid >> 6;
    const int wm = wid >> 1, wn = wid & 1;
    int colb, rowb;
    xcd_swizzle(colb, rowb);
    const long row0 = (long)rowb * 128;
    const long col0 = (long)colb * 128;

    const int sr = lane >> 2;
    const int skq = lane & 3;
    const ushort_t* Ag = A + (row0 + wid * 32 + sr) * (long)K + skq * 8;
    const ushort_t* Wg = W + (col0 + wid * 32 + sr) * (long)K + skq * 8;
    const int sa0 = (wid * 32) * 32, sa1 = (wid * 32 + 16) * 32;

    f32x4 acc[4][4] = {};
    const int lr = lane & 15;
    const int kg = lane >> 4;

    GLD16(Ag, &smem[0][sa0]);
    GLD16(Ag + 16 * (long)K, &smem[0][sa1]);
    GLD16(Wg, &smem[0][4096 + sa0]);
    GLD16(Wg + 16 * (long)K, &smem[0][4096 + sa1]);

    int pb = 0;
    for (int k0 = 0; k0 < K; k0 += 32, pb ^= 1) {
        __syncthreads();
        int kn = k0 + 32;
        if (kn < K) {
            GLD16(Ag + kn, &smem[pb ^ 1][sa0]);
            GLD16(Ag + 16 * (long)K + kn, &smem[pb ^ 1][sa1]);
            GLD16(Wg + kn, &smem[pb ^ 1][4096 + sa0]);
            GLD16(Wg + 16 * (long)K + kn, &smem[pb ^ 1][4096 + sa1]);
        }
        const ushort_t* Ab = smem[pb];
        const ushort_t* Wb = smem[pb] + 4096;
        short8 af[4], bfr[4];
#pragma unroll
        for (int i = 0; i < 4; i++)
            af[i] = *(const short8*)&Ab[(wm * 64 + i * 16 + lr) * 32 + kg * 8];
#pragma unroll
        for (int j = 0; j < 4; j++)
            bfr[j] = *(const short8*)&Wb[(wn * 64 + j * 16 + lr) * 32 + kg * 8];
#pragma unroll
        for (int i = 0; i < 4; i++)
#pragma unroll
            for (int j = 0; j < 4; j++)
                acc[i][j] = __builtin_amdgcn_mfma_f32_16x16x32_bf16(
                    af[i], bfr[j], acc[i][j], 0, 0, 0);
    }

#pragma unroll
    for (int i = 0; i < 4; i++) {
#pragma unroll
        for (int j = 0; j < 4; j++) {
            long row = row0 + wm * 64 + i * 16 + kg * 4;
            long col = col0 + wn * 64 + j * 16 + lr;
            float bv = bias ? bias[col] : 0.f;
#pragma unroll
            for (int r = 0; r < 4; r++) {
                float x = acc[i][j][r] + bv;
                if (relu) x = fmaxf(x, 0.f);
                size_t idx = (row + r) * (size_t)Cout + col;
                if (Ch)      Ch[idx] = (_Float16)x;
                else if (Cb) Cb[idx] = f2bf(x);
                else         C[idx] = x;
            }
        }
    }
}

// ---------------------------------------------------------------------------
// bf16 MFMA GEMM, tile 128x64, BK=32, 4 waves, each 32x64. Double-buffered.
// ---------------------------------------------------------------------------
__global__ __launch_bounds__(256)
void gemm_bf64(const ushort_t* __restrict__ A, const ushort_t* __restrict__ W,
               const float* __restrict__ bias, float* __restrict__ C,
               ushort_t* __restrict__ Cb, _Float16* __restrict__ Ch,
               int K, int Cout, int relu) {
    __shared__ __align__(16) ushort_t smem[2][6144];
    const int tid = threadIdx.x;
    const int lane = tid & 63;
    const int w = tid >> 6;
    int colb, rowb;
    xcd_swizzle(colb, rowb);
    const long row0 = (long)rowb * 128;
    const long col0 = (long)colb * 64;

    const int sr = lane >> 2;
    const int skq = lane & 3;
    const ushort_t* Ag = A + (row0 + w * 32 + sr) * (long)K + skq * 8;
    const ushort_t* Wg = W + (col0 + w * 16 + sr) * (long)K + skq * 8;
    const int sa0 = (w * 32) * 32, sa1 = (w * 32 + 16) * 32;
    const int sw0 = 4096 + (w * 16) * 32;

    f32x4 acc[2][4] = {};
    const int lr = lane & 15;
    const int kg = lane >> 4;

    GLD16(Ag, &smem[0][sa0]);
    GLD16(Ag + 16 * (long)K, &smem[0][sa1]);
    GLD16(Wg, &smem[0][sw0]);

    int pb = 0;
    for (int k0 = 0; k0 < K; k0 += 32, pb ^= 1) {
        __syncthreads();
        int kn = k0 + 32;
        if (kn < K) {
            GLD16(Ag + kn, &smem[pb ^ 1][sa0]);
            GLD16(Ag + 16 * (long)K + kn, &smem[pb ^ 1][sa1]);
            GLD16(Wg + kn, &smem[pb ^ 1][sw0]);
        }
        const ushort_t* Ab = smem[pb];
        const ushort_t* Wb = smem[pb] + 4096;
        short8 af[2], bfr[4];
#pragma unroll
        for (int i = 0; i < 2; i++)
            af[i] = *(const short8*)&Ab[(w * 32 + i * 16 + lr) * 32 + kg * 8];
#pragma unroll
        for (int j = 0; j < 4; j++)
            bfr[j] = *(const short8*)&Wb[(j * 16 + lr) * 32 + kg * 8];
#pragma unroll
        for (int i = 0; i < 2; i++)
#pragma unroll
            for (int j = 0; j < 4; j++)
                acc[i][j] = __builtin_amdgcn_mfma_f32_16x16x32_bf16(
                    af[i], bfr[j], acc[i][j], 0, 0, 0);
    }

#pragma unroll
    for (int i = 0; i < 2; i++) {
#pragma unroll
        for (int j = 0; j < 4; j++) {
            long row = row0 + w * 32 + i * 16 + kg * 4;
            long col = col0 + j * 16 + lr;
            float bv = bias ? bias[col] : 0.f;
#pragma unroll
            for (int r = 0; r < 4; r++) {
                float x = acc[i][j][r] + bv;
                if (relu) x = fmaxf(x, 0.f);
                size_t idx = (row + r) * (size_t)Cout + col;
                if (Ch)      Ch[idx] = (_Float16)x;
                else if (Cb) Cb[idx] = f2bf(x);
                else         C[idx] = x;
            }
        }
    }
}

// ---------------------------------------------------------------------------
// gemm_q_rot: 128x64-tile GEMM (Cout=512, K=512), col-block = one head.
// Double-buffered; epilogue Cs overlays staging LDS; rotates -> Qrot f16.
// ---------------------------------------------------------------------------
__global__ __launch_bounds__(256)
void gemm_q_rot(const ushort_t* __restrict__ A, const ushort_t* __restrict__ W,
                const float* __restrict__ bias,
                const float* __restrict__ sn, const float* __restrict__ cs,
                _Float16* __restrict__ Qrot) {
    __shared__ __align__(16) ushort_t smem[2][6144];
    _Float16* Cs = (_Float16*)smem;
    const int K = 512;
    const int tid = threadIdx.x;
    const int lane = tid & 63;
    const int w = tid >> 6;
    int colb, rowb;
    xcd_swizzle(colb, rowb);
    const long row0 = (long)rowb * 128;
    const int h = colb;
    const long col0 = (long)h * 64;

    const int sr = lane >> 2;
    const int skq = lane & 3;
    const ushort_t* Ag = A + (row0 + w * 32 + sr) * (long)K + skq * 8;
    const ushort_t* Wg = W + (col0 + w * 16 + sr) * (long)K + skq * 8;
    const int sa0 = (w * 32) * 32, sa1 = (w * 32 + 16) * 32;
    const int sw0 = 4096 + (w * 16) * 32;

    f32x4 acc[2][4] = {};
    const int lr = lane & 15;
    const int kg = lane >> 4;

    GLD16(Ag, &smem[0][sa0]);
    GLD16(Ag + 16 * (long)K, &smem[0][sa1]);
    GLD16(Wg, &smem[0][sw0]);

    int pb = 0;
    for (int k0 = 0; k0 < K; k0 += 32, pb ^= 1) {
        __syncthreads();
        int kn = k0 + 32;
        if (kn < K) {
            GLD16(Ag + kn, &smem[pb ^ 1][sa0]);
            GLD16(Ag + 16 * (long)K + kn, &smem[pb ^ 1][sa1]);
            GLD16(Wg + kn, &smem[pb ^ 1][sw0]);
        }
        const ushort_t* Ab = smem[pb];
        const ushort_t* Wb = smem[pb] + 4096;
        short8 af[2], bfr[4];
#pragma unroll
        for (int i = 0; i < 2; i++)
            af[i] = *(const short8*)&Ab[(w * 32 + i * 16 + lr) * 32 + kg * 8];
#pragma unroll
        for (int j = 0; j < 4; j++)
            bfr[j] = *(const short8*)&Wb[(j * 16 + lr) * 32 + kg * 8];
#pragma unroll
        for (int i = 0; i < 2; i++)
#pragma unroll
            for (int j = 0; j < 4; j++)
                acc[i][j] = __builtin_amdgcn_mfma_f32_16x16x32_bf16(
                    af[i], bfr[j], acc[i][j], 0, 0, 0);
    }

    __syncthreads();
#pragma unroll
    for (int i = 0; i < 2; i++)
#pragma unroll
        for (int j = 0; j < 4; j++) {
            int row = w * 32 + i * 16 + kg * 4;
            int col = j * 16 + lr;
            float bv = bias[col0 + col];
#pragma unroll
            for (int r = 0; r < 4; r++)
                Cs[(row + r) * 76 + col] = (_Float16)(acc[i][j][r] + bv);
        }
    __syncthreads();
    for (int idx = tid; idx < 4096; idx += 256) {
        int rr = idx >> 5, j = idx & 31;
        size_t srow = (size_t)row0 + rr;
        float x0 = (float)Cs[rr * 76 + 2 * j], x1 = (float)Cs[rr * 76 + 2 * j + 1];
        float s = sn[srow * 32 + j], c = cs[srow * 32 + j];
        Qrot[srow * 512 + h * 64 + j]      = (_Float16)(x0 * c - x1 * s);
        Qrot[srow * 512 + h * 64 + 32 + j] = (_Float16)(x1 * c + x0 * s);
    }
}

// ---------------------------------------------------------------------------
// gemm_kv: 128x128-tile GEMM (Cout=1024, K=512), col-block = one head's k|v.
// Double-buffered; epilogue: rotate k -> Krot, transpose v -> Vth.
// ---------------------------------------------------------------------------
__global__ __launch_bounds__(256)
void gemm_kv(const ushort_t* __restrict__ A, const ushort_t* __restrict__ W,
             const float* __restrict__ bias,
             const float* __restrict__ sn, const float* __restrict__ cs,
             _Float16* __restrict__ Krot, _Float16* __restrict__ Vth) {
    __shared__ __align__(16) ushort_t smem[2][8192];
    _Float16* Cs = (_Float16*)smem;
    const int K = 512;
    const int tid = threadIdx.x;
    const int lane = tid & 63;
    const int wid = tid >> 6;
    const int wm = wid >> 1, wn = wid & 1;
    int colb, rowb;
    xcd_swizzle(colb, rowb);
    const long row0 = (long)rowb * 128;
    const int h = colb;
    const long col0 = (long)h * 128;

    const int sr = lane >> 2;
    const int skq = lane & 3;
    const ushort_t* Ag = A + (row0 + wid * 32 + sr) * (long)K + skq * 8;
    const ushort_t* Wg = W + (col0 + wid * 32 + sr) * (long)K + skq * 8;
    const int sa0 = (wid * 32) * 32, sa1 = (wid * 32 + 16) * 32;

    f32x4 acc[4][4] = {};
    const int lr = lane & 15;
    const int kg = lane >> 4;

    GLD16(Ag, &smem[0][sa0]);
    GLD16(Ag + 16 * (long)K, &smem[0][sa1]);
    GLD16(Wg, &smem[0][4096 + sa0]);
    GLD16(Wg + 16 * (long)K, &smem[0][4096 + sa1]);

    int pb = 0;
    for (int k0 = 0; k0 < K; k0 += 32, pb ^= 1) {
        __syncthreads();
        int kn = k0 + 32;
        if (kn < K) {
            GLD16(Ag + kn, &smem[pb ^ 1][sa0]);
            GLD16(Ag + 16 * (long)K + kn, &smem[pb ^ 1][sa1]);
            GLD16(Wg + kn, &smem[pb ^ 1][4096 + sa0]);
            GLD16(Wg + 16 * (long)K + kn, &smem[pb ^ 1][4096 + sa1]);
        }
        const ushort_t* Ab = smem[pb];
        const ushort_t* Wb = smem[pb] + 4096;
        short8 af[4], bfr[4];
#pragma unroll
        for (int i = 0; i < 4; i++)
            af[i] = *(const short8*)&Ab[(wm * 64 + i * 16 + lr) * 32 + kg * 8];
#pragma unroll
        for (int j = 0; j < 4; j++)
            bfr[j] = *(const short8*)&Wb[(wn * 64 + j * 16 + lr) * 32 + kg * 8];
#pragma unroll
        for (int i = 0; i < 4; i++)
#pragma unroll
            for (int j = 0; j < 4; j++)
                acc[i][j] = __builtin_amdgcn_mfma_f32_16x16x32_bf16(
                    af[i], bfr[j], acc[i][j], 0, 0, 0);
    }

    const int b_ = (int)(row0 >> 10);
    const int m0_ = (int)(row0 & 1023);
#pragma unroll
    for (int half = 0; half < 2; half++) {
        __syncthreads();
        if (wn == half) {
#pragma unroll
            for (int i = 0; i < 4; i++)
#pragma unroll
                for (int j = 0; j < 4; j++) {
                    int row = wm * 64 + i * 16 + kg * 4;
                    int col = j * 16 + lr;
                    float bv = bias[col0 + half * 64 + col];
#pragma unroll
                    for (int r = 0; r < 4; r++)
                        Cs[(row + r) * 76 + col] = (_Float16)(acc[i][j][r] + bv);
                }
        }
        __syncthreads();
        if (half == 0) {
            for (int idx = tid; idx < 4096; idx += 256) {
                int rr = idx >> 5, j = idx & 31;
                size_t srow = (size_t)row0 + rr;
                float x0 = (float)Cs[rr * 76 + 2 * j], x1 = (float)Cs[rr * 76 + 2 * j + 1];
                float s = sn[srow * 32 + j], c = cs[srow * 32 + j];
                Krot[srow * 512 + h * 64 + j]      = (_Float16)(x0 * c - x1 * s);
                Krot[srow * 512 + h * 64 + 32 + j] = (_Float16)(x1 * c + x0 * s);
            }
        } else {
            for (int idx = tid; idx < 1024; idx += 256) {
                int d = idx >> 4, c = idx & 15;
                half8 v;
#pragma unroll
                for (int k = 0; k < 8; k++) v[k] = Cs[(c * 8 + k) * 76 + d];
                *(half8*)(Vth + (((size_t)(b_ * NHH + h)) * 64 + d) * MM
                          + m0_ + c * 8) = v;
            }
        }
    }
}

// ---------------------------------------------------------------------------
// One-shot fp32->bf16 convert of tgt, mem, and all 7 weight mats.
// ---------------------------------------------------------------------------
__global__ __launch_bounds__(256)
void cvt_all(const float* __restrict__ tgt, const float* __restrict__ mem,
             const float* __restrict__ w0, const float* __restrict__ w1,
             const float* __restrict__ w2, const float* __restrict__ w3,
             const float* __restrict__ w4, const float* __restrict__ w5,
             const float* __restrict__ w6,
             ushort_t* __restrict__ Abf, ushort_t* __restrict__ membf,
             ushort_t* __restrict__ Wbf) {
    int blk = blockIdx.x;
    const float* src;
    ushort_t* dst;
    size_t off;
    if (blk < 4096)       { src = tgt; dst = Abf;   off = (size_t)blk * 1024; }
    else if (blk < 12288) { src = mem; dst = membf; off = (size_t)(blk - 4096) * 1024; }
    else {
        int wb = blk - 12288;
        dst = Wbf + (size_t)wb * 1024;
        if (wb < 768)       { src = w0; off = (size_t)wb * 1024; }
        else if (wb < 1024) { src = w1; off = (size_t)(wb - 768) * 1024; }
        else if (wb < 1280) { src = w2; off = (size_t)(wb - 1024) * 1024; }
        else if (wb < 1792) { src = w3; off = (size_t)(wb - 1280) * 1024; }
        else if (wb < 2048) { src = w4; off = (size_t)(wb - 1792) * 1024; }
        else if (wb < 3072) { src = w5; off = (size_t)(wb - 2048) * 1024; }
        else                { src = w6; off = (size_t)(wb - 3072) * 1024; }
        float4 v = *(const float4*)(src + off + threadIdx.x * 4);
        ushort4 o;
        o.x = f2bf(v.x); o.y = f2bf(v.y); o.z = f2bf(v.z); o.w = f2bf(v.w);
        *(ushort4*)(dst + threadIdx.x * 4) = o;
        return;
    }
    float4 v = *(const float4*)(src + off + threadIdx.x * 4);
    ushort4 o;
    o.x = f2bf(v.x); o.y = f2bf(v.y); o.z = f2bf(v.z); o.w = f2bf(v.w);
    *(ushort4*)(dst + off + threadIdx.x * 4) = o;
}

// ---------------------------------------------------------------------------
// prep_vt: transpose 64-wide V slice per head (self-attention path).
// ---------------------------------------------------------------------------
__global__ __launch_bounds__(256)
void prep_vt(const _Float16* __restrict__ src, int L, int stride,
             int hmul, int hadd, _Float16* __restrict__ Vt) {
    const int b = blockIdx.z, h = blockIdx.y, m0 = blockIdx.x * 64;
    const int tid = threadIdx.x;
    __shared__ _Float16 vt[64][72];
    for (int idx = tid; idx < 512; idx += 256) {
        int m = idx >> 3, c = idx & 7;
        half8 v = *(const half8*)(src + ((size_t)(b * L + m0 + m)) * stride
                                  + h * hmul + hadd + c * 8);
#pragma unroll
        for (int k = 0; k < 8; k++) vt[c * 8 + k][m] = v[k];
    }
    __syncthreads();
    for (int idx = tid; idx < 512; idx += 256) {
        int d = idx >> 3, c = idx & 7;
        *(half8*)(Vt + (((size_t)(b * NHH + h)) * 64 + d) * L + m0 + c * 8)
            = *(const half8*)&vt[d][c * 8];
    }
}

// ---------------------------------------------------------------------------
// Flash MFMA attention v6 (== R11's attn5: 128 q/block, grid 512, __expf
// softmax, stride-76 conflict-free LDS). Resubmitted to test the flake
// hypothesis: both constituent changes passed individually (R8: 128q+__expf
// at stride 72; R10: stride 76 at 64q+exp2f); static audit shows no OOB
// writes and all LDS hazards barrier-protected.
// ---------------------------------------------------------------------------
__global__ __launch_bounds__(256)
void attn6(const _Float16* __restrict__ Q, int qstride, int qmul, int qadd,
           const _Float16* __restrict__ K, int kstride, int kmul, int kadd,
           const _Float16* __restrict__ Vt, int LV, int Lrows,
           ushort_t* __restrict__ out, int kvlen, int causal) {
    const int g = blockIdx.x;
    const int bh = (g & 7) * 16 + ((g >> 3) & 15);
    const int qb = g >> 7;
    const int b = bh >> 3, h = bh & 7;
    const int n0 = qb * 128;
    const int tid = threadIdx.x, lane = tid & 63, w = tid >> 6;
    const int quad = lane >> 4, l16 = lane & 15;
    const int qw = n0 + w * 32;

    __shared__ _Float16 Ks[64 * 76];
    __shared__ _Float16 Vs[64 * 76];
    __shared__ _Float16 Ps[4][32 * 76];
    _Float16* Pw = Ps[w];

    half8 bq[2][2];
#pragma unroll
    for (int s = 0; s < 2; s++)
#pragma unroll
        for (int c = 0; c < 2; c++)
            bq[s][c] = *(const half8*)(Q + ((size_t)(b * NN + qw + s * 16 + l16)) * qstride
                                       + h * qmul + qadd + c * 32 + quad * 8);

    f32x4 acc[2][4] = {};
    float mrun[2] = {-3e38f, -3e38f}, lrun[2] = {0.f, 0.f};

    const int srow = tid >> 3;
    const int scol = (tid & 7) * 8;
    const int limit = causal ? (n0 + 128) : kvlen;

    half8 kr0, kr1, vr0, vr1;
    {
        size_t kb = ((size_t)(b * Lrows + srow)) * kstride + h * kmul + kadd + scol;
        kr0 = *(const half8*)(K + kb);
        kr1 = *(const half8*)(K + kb + (size_t)32 * kstride);
        size_t vb = (((size_t)(b * NHH + h)) * 64 + srow) * (size_t)LV + scol;
        vr0 = *(const half8*)(Vt + vb);
        vr1 = *(const half8*)(Vt + vb + (size_t)32 * LV);
    }

    for (int key0 = 0; key0 < limit; key0 += 64) {
        __syncthreads();
        *(half8*)&Ks[srow * 76 + scol] = kr0;
        *(half8*)&Ks[(srow + 32) * 76 + scol] = kr1;
        *(half8*)&Vs[srow * 76 + scol] = vr0;
        *(half8*)&Vs[(srow + 32) * 76 + scol] = vr1;
        __syncthreads();
        int knext = key0 + 64;
        if (knext < limit) {
            size_t kb = ((size_t)(b * Lrows + knext + srow)) * kstride
                        + h * kmul + kadd + scol;
            kr0 = *(const half8*)(K + kb);
            kr1 = *(const half8*)(K + kb + (size_t)32 * kstride);
            size_t vb = (((size_t)(b * NHH + h)) * 64 + srow) * (size_t)LV
                        + knext + scol;
            vr0 = *(const half8*)(Vt + vb);
            vr1 = *(const half8*)(Vt + vb + (size_t)32 * LV);
        }
        if (causal && key0 > qw + 31) continue;

        f32x4 st[2][4];
#pragma unroll
        for (int kt = 0; kt < 4; kt++) {
            half8 ak0 = *(const half8*)&Ks[(kt * 16 + l16) * 76 + quad * 8];
            half8 ak1 = *(const half8*)&Ks[(kt * 16 + l16) * 76 + 32 + quad * 8];
#pragma unroll
            for (int s = 0; s < 2; s++) {
                f32x4 z = {};
                z = __builtin_amdgcn_mfma_f32_16x16x32_f16(ak0, bq[s][0], z, 0, 0, 0);
                z = __builtin_amdgcn_mfma_f32_16x16x32_f16(ak1, bq[s][1], z, 0, 0, 0);
                st[s][kt] = z;
            }
        }
        if (causal && key0 + 64 > qw) {
#pragma unroll
            for (int s = 0; s < 2; s++) {
                int qabs = qw + s * 16 + l16;
#pragma unroll
                for (int kt = 0; kt < 4; kt++)
#pragma unroll
                    for (int r = 0; r < 4; r++)
                        if (key0 + kt * 16 + quad * 4 + r > qabs)
                            st[s][kt][r] = -3e38f;
            }
        }
#pragma unroll
        for (int s = 0; s < 2; s++) {
            float lm = -3e38f;
#pragma unroll
            for (int kt = 0; kt < 4; kt++)
                lm = fmaxf(lm, fmaxf(fmaxf(st[s][kt][0], st[s][kt][1]),
                                     fmaxf(st[s][kt][2], st[s][kt][3])));
            lm = fmaxf(lm, __shfl_xor(lm, 16));
            lm = fmaxf(lm, __shfl_xor(lm, 32));
            float mnew = fmaxf(mrun[s], lm);
            float corr = __expf((mrun[s] - mnew) * 0.125f);
            mrun[s] = mnew;
            float ls = 0.f;
#pragma unroll
            for (int kt = 0; kt < 4; kt++) {
                half4 ph;
#pragma unroll
                for (int r = 0; r < 4; r++) {
                    float p = __expf((st[s][kt][r] - mnew) * 0.125f);
                    ls += p;
                    ph[r] = (_Float16)p;
                }
                *(half4*)&Pw[(s * 16 + l16) * 76 + kt * 16 + quad * 4] = ph;
            }
            ls += __shfl_xor(ls, 16);
            ls += __shfl_xor(ls, 32);
            lrun[s] = lrun[s] * corr + ls;
            float cb0 = __shfl(corr, (lane & 48) | (quad * 4 + 0));
            float cb1 = __shfl(corr, (lane & 48) | (quad * 4 + 1));
            float cb2 = __shfl(corr, (lane & 48) | (quad * 4 + 2));
            float cb3 = __shfl(corr, (lane & 48) | (quad * 4 + 3));
#pragma unroll
            for (int dt = 0; dt < 4; dt++) {
                acc[s][dt][0] *= cb0; acc[s][dt][1] *= cb1;
                acc[s][dt][2] *= cb2; acc[s][dt][3] *= cb3;
            }
        }
        half8 ap[2][2];
#pragma unroll
        for (int s = 0; s < 2; s++)
#pragma unroll
            for (int c = 0; c < 2; c++)
                ap[s][c] = *(const half8*)&Pw[(s * 16 + l16) * 76 + c * 32 + quad * 8];
#pragma unroll
        for (int dt = 0; dt < 4; dt++) {
            half8 bv0 = *(const half8*)&Vs[(dt * 16 + l16) * 76 + quad * 8];
            half8 bv1 = *(const half8*)&Vs[(dt * 16 + l16) * 76 + 32 + quad * 8];
#pragma unroll
            for (int s = 0; s < 2; s++) {
                acc[s][dt] = __builtin_amdgcn_mfma_f32_16x16x32_f16(ap[s][0], bv0, acc[s][dt], 0, 0, 0);
                acc[s][dt] = __builtin_amdgcn_mfma_f32_16x16x32_f16(ap[s][1], bv1, acc[s][dt], 0, 0, 0);
            }
        }
    }
#pragma unroll
    for (int s = 0; s < 2; s++) {
        float invq = 1.f / lrun[s];
        float iv0 = __shfl(invq, (lane & 48) | (quad * 4 + 0));
        float iv1 = __shfl(invq, (lane & 48) | (quad * 4 + 1));
        float iv2 = __shfl(invq, (lane & 48) | (quad * 4 + 2));
        float iv3 = __shfl(invq, (lane & 48) | (quad * 4 + 3));
#pragma unroll
        for (int dt = 0; dt < 4; dt++) {
            size_t base = ((size_t)(b * NN + qw + s * 16 + quad * 4)) * 512
                          + h * 64 + dt * 16 + l16;
            out[base]           = f2bf(acc[s][dt][0] * iv0);
            out[base + 512]     = f2bf(acc[s][dt][1] * iv1);
            out[base + 1024]    = f2bf(acc[s][dt][2] * iv2);
            out[base + 1536]    = f2bf(acc[s][dt][3] * iv3);
        }
    }
}

// ---------------------------------------------------------------------------
// out = LayerNorm(sum_{s<nsplit} u[s] + res)*g + beta; optional bf16 copy.
// ---------------------------------------------------------------------------
__global__ __launch_bounds__(256)
void ln_residual(const float* __restrict__ u, int nsplit,
                 const float* __restrict__ res,
                 const float* __restrict__ g, const float* __restrict__ be,
                 float* __restrict__ out, ushort_t* __restrict__ outbf) {
    const int row = blockIdx.x, t = threadIdx.x;
    const float* rp = res + (size_t)row * HIDD;
    float z0 = rp[t];
    float z1 = rp[t + 256];
    for (int s = 0; s < nsplit; s++) {
        const float* up = u + (size_t)s * 4194304 + (size_t)row * HIDD;
        z0 += up[t];
        z1 += up[t + 256];
    }
    float sm = z0 + z1, s2 = z0 * z0 + z1 * z1;
#pragma unroll
    for (int off = 1; off < 64; off <<= 1) {
        sm += __shfl_xor(sm, off, 64);
        s2 += __shfl_xor(s2, off, 64);
    }
    __shared__ float ps[4], ps2[4];
    int w = t >> 6;
    if ((t & 63) == 0) { ps[w] = sm; ps2[w] = s2; }
    __syncthreads();
    sm = ps[0] + ps[1] + ps[2] + ps[3];
    s2 = ps2[0] + ps2[1] + ps2[2] + ps2[3];
    float mu = sm * (1.f / 512.f);
    float var = s2 * (1.f / 512.f) - mu * mu;
    float rstd = rsqrtf(var + 1e-5f);
    float y0 = (z0 - mu) * rstd * g[t] + be[t];
    float y1 = (z1 - mu) * rstd * g[t + 256] + be[t + 256];
    out[(size_t)row * HIDD + t]       = y0;
    out[(size_t)row * HIDD + t + 256] = y1;
    if (outbf) {
        outbf[(size_t)row * HIDD + t]       = f2bf(y0);
        outbf[(size_t)row * HIDD + t + 256] = f2bf(y1);
    }
}

// ---------------------------------------------------------------------------
extern "C" void kernel_launch(void* const* d_in, const int* in_sizes, int n_in,
                              void* d_out, int out_size, void* d_ws, size_t ws_size,
                              hipStream_t stream) {
    const float* tgt      = (const float*)d_in[0];
    const float* mem      = (const float*)d_in[1];
    const float* pep_sin  = (const float*)d_in[2];
    const float* pep_cos  = (const float*)d_in[3];
    const float* pk_sin   = (const float*)d_in[4];
    const float* pk_cos   = (const float*)d_in[5];
    const float* mmha_w   = (const float*)d_in[8];
    const float* mmha_b   = (const float*)d_in[9];
    const float* mmha_ow  = (const float*)d_in[10];
    const float* mmha_ob  = (const float*)d_in[11];
    const float* mmha_g   = (const float*)d_in[12];
    const float* mmha_be  = (const float*)d_in[13];
    const float* mha_qw   = (const float*)d_in[14];
    const float* mha_qb   = (const float*)d_in[15];
    const float* mha_kvw  = (const float*)d_in[16];
    const float* mha_kvb  = (const float*)d_in[17];
    const float* mha_ow   = (const float*)d_in[18];
    const float* mha_ob   = (const float*)d_in[19];
    const float* mha_g    = (const float*)d_in[20];
    const float* mha_be   = (const float*)d_in[21];
    const float* ffn_w1   = (const float*)d_in[22];
    const float* ffn_w2   = (const float*)d_in[23];
    const float* ffn_g    = (const float*)d_in[24];
    const float* ffn_be   = (const float*)d_in[25];

    float* ws = (float*)d_ws;
    float* utmp  = ws;                        //  4,194,304 f32
    float* tgt12 = ws + 4194304;              //  4,194,304 f32
    _Float16* hp = (_Float16*)(ws + 8388608); // half pool (offsets in halves)
    _Float16* qkvh  = hp;                     // 12,582,912 (B*N*1536)
    _Float16* Qrot  = hp + 12582912;          //  4,194,304
    _Float16* Vth   = hp + 16777216;          //  8,388,608 (self uses half)
    _Float16* Krot  = hp + 25165824;          //  8,388,608
    ushort_t* membf = (ushort_t*)(hp + 33554432); // 8,388,608 bf16
    ushort_t* Abf   = (ushort_t*)(hp + 41943040); // 4,194,304 bf16
    ushort_t* Wbf   = (ushort_t*)(hp + 46137344); // 4,194,304 bf16 weights
    ushort_t* w_mmha = Wbf;                   //   786,432
    ushort_t* w_mmow = Wbf + 786432;          //   262,144
    ushort_t* w_qw   = Wbf + 1048576;         //   262,144
    ushort_t* w_kvw  = Wbf + 1310720;         //   524,288
    ushort_t* w_mow  = Wbf + 1835008;         //   262,144
    ushort_t* w_f1   = Wbf + 2097152;         // 1,048,576
    ushort_t* w_f2   = Wbf + 3145728;         // 1,048,576
    ushort_t* hbf = (ushort_t*)qkvh;          // ffn hidden bf16 spans qkvh+Qrot
    float* out = (float*)d_out;
    (void)in_sizes; (void)n_in; (void)out_size; (void)ws_size;

    // 0. all fp32->bf16 converts in one launch
    cvt_all<<<16384, 256, 0, stream>>>(tgt, mem, mmha_w, mmha_ow, mha_qw,
                                       mha_kvw, mha_ow, ffn_w1, ffn_w2,
                                       Abf, membf, Wbf);
    // 1. qkv = tgt @ mmha_w.T + b  (8192x512x1536, f16 out)
    gemm_bf<<<dim3(12, 64), 256, 0, stream>>>(Abf, w_mmha, mmha_b, nullptr, nullptr, qkvh, 512, 1536, 0);
    // 2. self-attention (causal), 128 q/block
    prep_vt<<<dim3(8, NHH, BB), 256, 0, stream>>>(qkvh, NN, 1536, 192, 128, Vth);
    attn6<<<512, 256, 0, stream>>>(qkvh, 1536, 192, 0, qkvh, 1536, 192, 64,
                                   Vth, NN, NN, Abf, 0, 1);
    // 3. tgt1 = LN(x @ ow.T + ob + tgt)
    gemm_bf64<<<dim3(8, 64), 256, 0, stream>>>(Abf, w_mmow, mmha_ob, utmp, nullptr, nullptr, 512, 512, 0);
    ln_residual<<<8192, 256, 0, stream>>>(utmp, 1, tgt, mmha_g, mmha_be, tgt12, Abf);
    // 4. Qrot = rot(tgt1 @ qw.T + qb)
    gemm_q_rot<<<dim3(8, 64), 256, 0, stream>>>(Abf, w_qw, mha_qb, pep_sin, pep_cos, Qrot);
    // 5. kv GEMM with fused k-rotation + v-transpose epilogue
    gemm_kv<<<dim3(8, 128), 256, 0, stream>>>(membf, w_kvw, mha_kvb, pk_sin, pk_cos, Krot, Vth);
    // 6. cross-attention (960 valid keys), 128 q/block
    attn6<<<512, 256, 0, stream>>>(Qrot, 512, 64, 0, Krot, 512, 64, 0,
                                   Vth, MM, MM, Abf, MM - 64, 0);
    // 7. tgt2 = LN(x2 @ ow.T + ob + tgt1)
    gemm_bf64<<<dim3(8, 64), 256, 0, stream>>>(Abf, w_mow, mha_ob, utmp, nullptr, nullptr, 512, 512, 0);
    ln_residual<<<8192, 256, 0, stream>>>(utmp, 1, tgt12, mha_g, mha_be, tgt12, Abf);
    // 8. h = relu(tgt2 @ w1.T)     (8192x512x2048, bf16 out)
    gemm_bf<<<dim3(16, 64), 256, 0, stream>>>(Abf, w_f1, nullptr, nullptr, hbf, nullptr, 512, 2048, 1);
    // 9. h2 = h @ w2.T  (8192x2048x512) 128x64 tiles, full K, XCD-swizzled
    gemm_bf64<<<dim3(8, 64), 256, 0, stream>>>(hbf, w_f2, nullptr, utmp, nullptr, nullptr, 2048, 512, 0);
    // 10. out = LN(tgt2 + h2)
    ln_residual<<<8192, 256, 0, stream>>>(utmp, 1, tgt12, ffn_g, ffn_be, out, nullptr);
}

// Round 13
// 410.544 us; speedup vs baseline: 1.0704x; 1.0173x over previous
//
#include <hip/hip_runtime.h>
#include <hip/hip_bf16.h>

// Problem constants: B,N,M,HID,NH = 16,512,1024,512,8; HS=64
#define BB 16
#define NN 512
#define MM 1024
#define HIDD 512
#define NHH 8

typedef unsigned short ushort_t;
typedef __attribute__((ext_vector_type(8))) short short8;      // 8 bf16
typedef __attribute__((ext_vector_type(8))) _Float16 half8;    // 8 fp16
typedef __attribute__((ext_vector_type(4))) _Float16 half4;
typedef __attribute__((ext_vector_type(4))) float f32x4;

__device__ __forceinline__ ushort_t f2bf(float x) {   // RNE fp32->bf16
    unsigned u = __float_as_uint(x);
    u += 0x7fff + ((u >> 16) & 1);
    return (ushort_t)(u >> 16);
}

// async global->LDS, 16B per lane (GEMM staging; layout contiguous per wave)
#define GLD16(g, l) __builtin_amdgcn_global_load_lds(                      \
    (const __attribute__((address_space(1))) void*)(g),                    \
    (__attribute__((address_space(3))) void*)(l), 16, 0, 0)

// XCD-aware swizzle: consecutive linear block ids land on XCD id%8.
__device__ __forceinline__ void xcd_swizzle(int& colb, int& rowb) {
    int id = blockIdx.x + blockIdx.y * gridDim.x;
    int C = gridDim.x;
    int xcd = id & 7;
    int slot = id >> 3;
    int rows_per = gridDim.y >> 3;
    colb = slot % C;
    rowb = xcd * rows_per + slot / C;
}

// ---------------------------------------------------------------------------
// bf16 MFMA GEMM, tile 128x128, BK=32, 4 waves (2x2 of 64x64). Double-buffered.
// ---------------------------------------------------------------------------
__global__ __launch_bounds__(256)
void gemm_bf(const ushort_t* __restrict__ A, const ushort_t* __restrict__ W,
             const float* __restrict__ bias, float* __restrict__ C,
             ushort_t* __restrict__ Cb, _Float16* __restrict__ Ch,
             int K, int Cout, int relu) {
    __shared__ __align__(16) ushort_t smem[2][8192];
    const int tid = threadIdx.x;
    const int lane = tid & 63;
    const int wid = tid >> 6;
    const int wm = wid >> 1, wn = wid & 1;
    int colb, rowb;
    xcd_swizzle(colb, rowb);
    const long row0 = (long)rowb * 128;
    const long col0 = (long)colb * 128;

    const int sr = lane >> 2;
    const int skq = lane & 3;
    const ushort_t* Ag = A + (row0 + wid * 32 + sr) * (long)K + skq * 8;
    const ushort_t* Wg = W + (col0 + wid * 32 + sr) * (long)K + skq * 8;
    const int sa0 = (wid * 32) * 32, sa1 = (wid * 32 + 16) * 32;

    f32x4 acc[4][4] = {};
    const int lr = lane & 15;
    const int kg = lane >> 4;

    GLD16(Ag, &smem[0][sa0]);
    GLD16(Ag + 16 * (long)K, &smem[0][sa1]);
    GLD16(Wg, &smem[0][4096 + sa0]);
    GLD16(Wg + 16 * (long)K, &smem[0][4096 + sa1]);

    int pb = 0;
    for (int k0 = 0; k0 < K; k0 += 32, pb ^= 1) {
        __syncthreads();
        int kn = k0 + 32;
        if (kn < K) {
            GLD16(Ag + kn, &smem[pb ^ 1][sa0]);
            GLD16(Ag + 16 * (long)K + kn, &smem[pb ^ 1][sa1]);
            GLD16(Wg + kn, &smem[pb ^ 1][4096 + sa0]);
            GLD16(Wg + 16 * (long)K + kn, &smem[pb ^ 1][4096 + sa1]);
        }
        const ushort_t* Ab = smem[pb];
        const ushort_t* Wb = smem[pb] + 4096;
        short8 af[4], bfr[4];
#pragma unroll
        for (int i = 0; i < 4; i++)
            af[i] = *(const short8*)&Ab[(wm * 64 + i * 16 + lr) * 32 + kg * 8];
#pragma unroll
        for (int j = 0; j < 4; j++)
            bfr[j] = *(const short8*)&Wb[(wn * 64 + j * 16 + lr) * 32 + kg * 8];
#pragma unroll
        for (int i = 0; i < 4; i++)
#pragma unroll
            for (int j = 0; j < 4; j++)
                acc[i][j] = __builtin_amdgcn_mfma_f32_16x16x32_bf16(
                    af[i], bfr[j], acc[i][j], 0, 0, 0);
    }

#pragma unroll
    for (int i = 0; i < 4; i++) {
#pragma unroll
        for (int j = 0; j < 4; j++) {
            long row = row0 + wm * 64 + i * 16 + kg * 4;
            long col = col0 + wn * 64 + j * 16 + lr;
            float bv = bias ? bias[col] : 0.f;
#pragma unroll
            for (int r = 0; r < 4; r++) {
                float x = acc[i][j][r] + bv;
                if (relu) x = fmaxf(x, 0.f);
                size_t idx = (row + r) * (size_t)Cout + col;
                if (Ch)      Ch[idx] = (_Float16)x;
                else if (Cb) Cb[idx] = f2bf(x);
                else         C[idx] = x;
            }
        }
    }
}

// ---------------------------------------------------------------------------
// bf16 MFMA GEMM, tile 128x64, BK=32, 4 waves, each 32x64. Double-buffered.
// ---------------------------------------------------------------------------
__global__ __launch_bounds__(256)
void gemm_bf64(const ushort_t* __restrict__ A, const ushort_t* __restrict__ W,
               const float* __restrict__ bias, float* __restrict__ C,
               ushort_t* __restrict__ Cb, _Float16* __restrict__ Ch,
               int K, int Cout, int relu) {
    __shared__ __align__(16) ushort_t smem[2][6144];
    const int tid = threadIdx.x;
    const int lane = tid & 63;
    const int w = tid >> 6;
    int colb, rowb;
    xcd_swizzle(colb, rowb);
    const long row0 = (long)rowb * 128;
    const long col0 = (long)colb * 64;

    const int sr = lane >> 2;
    const int skq = lane & 3;
    const ushort_t* Ag = A + (row0 + w * 32 + sr) * (long)K + skq * 8;
    const ushort_t* Wg = W + (col0 + w * 16 + sr) * (long)K + skq * 8;
    const int sa0 = (w * 32) * 32, sa1 = (w * 32 + 16) * 32;
    const int sw0 = 4096 + (w * 16) * 32;

    f32x4 acc[2][4] = {};
    const int lr = lane & 15;
    const int kg = lane >> 4;

    GLD16(Ag, &smem[0][sa0]);
    GLD16(Ag + 16 * (long)K, &smem[0][sa1]);
    GLD16(Wg, &smem[0][sw0]);

    int pb = 0;
    for (int k0 = 0; k0 < K; k0 += 32, pb ^= 1) {
        __syncthreads();
        int kn = k0 + 32;
        if (kn < K) {
            GLD16(Ag + kn, &smem[pb ^ 1][sa0]);
            GLD16(Ag + 16 * (long)K + kn, &smem[pb ^ 1][sa1]);
            GLD16(Wg + kn, &smem[pb ^ 1][sw0]);
        }
        const ushort_t* Ab = smem[pb];
        const ushort_t* Wb = smem[pb] + 4096;
        short8 af[2], bfr[4];
#pragma unroll
        for (int i = 0; i < 2; i++)
            af[i] = *(const short8*)&Ab[(w * 32 + i * 16 + lr) * 32 + kg * 8];
#pragma unroll
        for (int j = 0; j < 4; j++)
            bfr[j] = *(const short8*)&Wb[(j * 16 + lr) * 32 + kg * 8];
#pragma unroll
        for (int i = 0; i < 2; i++)
#pragma unroll
            for (int j = 0; j < 4; j++)
                acc[i][j] = __builtin_amdgcn_mfma_f32_16x16x32_bf16(
                    af[i], bfr[j], acc[i][j], 0, 0, 0);
    }

#pragma unroll
    for (int i = 0; i < 2; i++) {
#pragma unroll
        for (int j = 0; j < 4; j++) {
            long row = row0 + w * 32 + i * 16 + kg * 4;
            long col = col0 + j * 16 + lr;
            float bv = bias ? bias[col] : 0.f;
#pragma unroll
            for (int r = 0; r < 4; r++) {
                float x = acc[i][j][r] + bv;
                if (relu) x = fmaxf(x, 0.f);
                size_t idx = (row + r) * (size_t)Cout + col;
                if (Ch)      Ch[idx] = (_Float16)x;
                else if (Cb) Cb[idx] = f2bf(x);
                else         C[idx] = x;
            }
        }
    }
}

// ---------------------------------------------------------------------------
// gemm_q_rot: 128x64-tile GEMM (Cout=512, K=512), col-block = one head.
// Double-buffered; epilogue Cs overlays staging LDS; rotates -> Qrot f16.
// ---------------------------------------------------------------------------
__global__ __launch_bounds__(256)
void gemm_q_rot(const ushort_t* __restrict__ A, const ushort_t* __restrict__ W,
                const float* __restrict__ bias,
                const float* __restrict__ sn, const float* __restrict__ cs,
                _Float16* __restrict__ Qrot) {
    __shared__ __align__(16) ushort_t smem[2][6144];
    _Float16* Cs = (_Float16*)smem;
    const int K = 512;
    const int tid = threadIdx.x;
    const int lane = tid & 63;
    const int w = tid >> 6;
    int colb, rowb;
    xcd_swizzle(colb, rowb);
    const long row0 = (long)rowb * 128;
    const int h = colb;
    const long col0 = (long)h * 64;

    const int sr = lane >> 2;
    const int skq = lane & 3;
    const ushort_t* Ag = A + (row0 + w * 32 + sr) * (long)K + skq * 8;
    const ushort_t* Wg = W + (col0 + w * 16 + sr) * (long)K + skq * 8;
    const int sa0 = (w * 32) * 32, sa1 = (w * 32 + 16) * 32;
    const int sw0 = 4096 + (w * 16) * 32;

    f32x4 acc[2][4] = {};
    const int lr = lane & 15;
    const int kg = lane >> 4;

    GLD16(Ag, &smem[0][sa0]);
    GLD16(Ag + 16 * (long)K, &smem[0][sa1]);
    GLD16(Wg, &smem[0][sw0]);

    int pb = 0;
    for (int k0 = 0; k0 < K; k0 += 32, pb ^= 1) {
        __syncthreads();
        int kn = k0 + 32;
        if (kn < K) {
            GLD16(Ag + kn, &smem[pb ^ 1][sa0]);
            GLD16(Ag + 16 * (long)K + kn, &smem[pb ^ 1][sa1]);
            GLD16(Wg + kn, &smem[pb ^ 1][sw0]);
        }
        const ushort_t* Ab = smem[pb];
        const ushort_t* Wb = smem[pb] + 4096;
        short8 af[2], bfr[4];
#pragma unroll
        for (int i = 0; i < 2; i++)
            af[i] = *(const short8*)&Ab[(w * 32 + i * 16 + lr) * 32 + kg * 8];
#pragma unroll
        for (int j = 0; j < 4; j++)
            bfr[j] = *(const short8*)&Wb[(j * 16 + lr) * 32 + kg * 8];
#pragma unroll
        for (int i = 0; i < 2; i++)
#pragma unroll
            for (int j = 0; j < 4; j++)
                acc[i][j] = __builtin_amdgcn_mfma_f32_16x16x32_bf16(
                    af[i], bfr[j], acc[i][j], 0, 0, 0);
    }

    __syncthreads();
#pragma unroll
    for (int i = 0; i < 2; i++)
#pragma unroll
        for (int j = 0; j < 4; j++) {
            int row = w * 32 + i * 16 + kg * 4;
            int col = j * 16 + lr;
            float bv = bias[col0 + col];
#pragma unroll
            for (int r = 0; r < 4; r++)
                Cs[(row + r) * 76 + col] = (_Float16)(acc[i][j][r] + bv);
        }
    __syncthreads();
    for (int idx = tid; idx < 4096; idx += 256) {
        int rr = idx >> 5, j = idx & 31;
        size_t srow = (size_t)row0 + rr;
        float x0 = (float)Cs[rr * 76 + 2 * j], x1 = (float)Cs[rr * 76 + 2 * j + 1];
        float s = sn[srow * 32 + j], c = cs[srow * 32 + j];
        Qrot[srow * 512 + h * 64 + j]      = (_Float16)(x0 * c - x1 * s);
        Qrot[srow * 512 + h * 64 + 32 + j] = (_Float16)(x1 * c + x0 * s);
    }
}

// ---------------------------------------------------------------------------
// gemm_kv: 128x128-tile GEMM (Cout=1024, K=512), col-block = one head's k|v.
// Double-buffered; epilogue: rotate k -> Krot, transpose v -> Vth.
// ---------------------------------------------------------------------------
__global__ __launch_bounds__(256)
void gemm_kv(const ushort_t* __restrict__ A, const ushort_t* __restrict__ W,
             const float* __restrict__ bias,
             const float* __restrict__ sn, const float* __restrict__ cs,
             _Float16* __restrict__ Krot, _Float16* __restrict__ Vth) {
    __shared__ __align__(16) ushort_t smem[2][8192];
    _Float16* Cs = (_Float16*)smem;
    const int K = 512;
    const int tid = threadIdx.x;
    const int lane = tid & 63;
    const int wid = tid >> 6;
    const int wm = wid >> 1, wn = wid & 1;
    int colb, rowb;
    xcd_swizzle(colb, rowb);
    const long row0 = (long)rowb * 128;
    const int h = colb;
    const long col0 = (long)h * 128;

    const int sr = lane >> 2;
    const int skq = lane & 3;
    const ushort_t* Ag = A + (row0 + wid * 32 + sr) * (long)K + skq * 8;
    const ushort_t* Wg = W + (col0 + wid * 32 + sr) * (long)K + skq * 8;
    const int sa0 = (wid * 32) * 32, sa1 = (wid * 32 + 16) * 32;

    f32x4 acc[4][4] = {};
    const int lr = lane & 15;
    const int kg = lane >> 4;

    GLD16(Ag, &smem[0][sa0]);
    GLD16(Ag + 16 * (long)K, &smem[0][sa1]);
    GLD16(Wg, &smem[0][4096 + sa0]);
    GLD16(Wg + 16 * (long)K, &smem[0][4096 + sa1]);

    int pb = 0;
    for (int k0 = 0; k0 < K; k0 += 32, pb ^= 1) {
        __syncthreads();
        int kn = k0 + 32;
        if (kn < K) {
            GLD16(Ag + kn, &smem[pb ^ 1][sa0]);
            GLD16(Ag + 16 * (long)K + kn, &smem[pb ^ 1][sa1]);
            GLD16(Wg + kn, &smem[pb ^ 1][4096 + sa0]);
            GLD16(Wg + 16 * (long)K + kn, &smem[pb ^ 1][4096 + sa1]);
        }
        const ushort_t* Ab = smem[pb];
        const ushort_t* Wb = smem[pb] + 4096;
        short8 af[4], bfr[4];
#pragma unroll
        for (int i = 0; i < 4; i++)
            af[i] = *(const short8*)&Ab[(wm * 64 + i * 16 + lr) * 32 + kg * 8];
#pragma unroll
        for (int j = 0; j < 4; j++)
            bfr[j] = *(const short8*)&Wb[(wn * 64 + j * 16 + lr) * 32 + kg * 8];
#pragma unroll
        for (int i = 0; i < 4; i++)
#pragma unroll
            for (int j = 0; j < 4; j++)
                acc[i][j] = __builtin_amdgcn_mfma_f32_16x16x32_bf16(
                    af[i], bfr[j], acc[i][j], 0, 0, 0);
    }

    const int b_ = (int)(row0 >> 10);
    const int m0_ = (int)(row0 & 1023);
#pragma unroll
    for (int half = 0; half < 2; half++) {
        __syncthreads();
        if (wn == half) {
#pragma unroll
            for (int i = 0; i < 4; i++)
#pragma unroll
                for (int j = 0; j < 4; j++) {
                    int row = wm * 64 + i * 16 + kg * 4;
                    int col = j * 16 + lr;
                    float bv = bias[col0 + half * 64 + col];
#pragma unroll
                    for (int r = 0; r < 4; r++)
                        Cs[(row + r) * 76 + col] = (_Float16)(acc[i][j][r] + bv);
                }
        }
        __syncthreads();
        if (half == 0) {
            for (int idx = tid; idx < 4096; idx += 256) {
                int rr = idx >> 5, j = idx & 31;
                size_t srow = (size_t)row0 + rr;
                float x0 = (float)Cs[rr * 76 + 2 * j], x1 = (float)Cs[rr * 76 + 2 * j + 1];
                float s = sn[srow * 32 + j], c = cs[srow * 32 + j];
                Krot[srow * 512 + h * 64 + j]      = (_Float16)(x0 * c - x1 * s);
                Krot[srow * 512 + h * 64 + 32 + j] = (_Float16)(x1 * c + x0 * s);
            }
        } else {
            for (int idx = tid; idx < 1024; idx += 256) {
                int d = idx >> 4, c = idx & 15;
                half8 v;
#pragma unroll
                for (int k = 0; k < 8; k++) v[k] = Cs[(c * 8 + k) * 76 + d];
                *(half8*)(Vth + (((size_t)(b_ * NHH + h)) * 64 + d) * MM
                          + m0_ + c * 8) = v;
            }
        }
    }
}

// ---------------------------------------------------------------------------
// One-shot fp32->bf16 convert of tgt, mem, and all 7 weight mats.
// ---------------------------------------------------------------------------
__global__ __launch_bounds__(256)
void cvt_all(const float* __restrict__ tgt, const float* __restrict__ mem,
             const float* __restrict__ w0, const float* __restrict__ w1,
             const float* __restrict__ w2, const float* __restrict__ w3,
             const float* __restrict__ w4, const float* __restrict__ w5,
             const float* __restrict__ w6,
             ushort_t* __restrict__ Abf, ushort_t* __restrict__ membf,
             ushort_t* __restrict__ Wbf) {
    int blk = blockIdx.x;
    const float* src;
    ushort_t* dst;
    size_t off;
    if (blk < 4096)       { src = tgt; dst = Abf;   off = (size_t)blk * 1024; }
    else if (blk < 12288) { src = mem; dst = membf; off = (size_t)(blk - 4096) * 1024; }
    else {
        int wb = blk - 12288;
        dst = Wbf + (size_t)wb * 1024;
        if (wb < 768)       { src = w0; off = (size_t)wb * 1024; }
        else if (wb < 1024) { src = w1; off = (size_t)(wb - 768) * 1024; }
        else if (wb < 1280) { src = w2; off = (size_t)(wb - 1024) * 1024; }
        else if (wb < 1792) { src = w3; off = (size_t)(wb - 1280) * 1024; }
        else if (wb < 2048) { src = w4; off = (size_t)(wb - 1792) * 1024; }
        else if (wb < 3072) { src = w5; off = (size_t)(wb - 2048) * 1024; }
        else                { src = w6; off = (size_t)(wb - 3072) * 1024; }
        float4 v = *(const float4*)(src + off + threadIdx.x * 4);
        ushort4 o;
        o.x = f2bf(v.x); o.y = f2bf(v.y); o.z = f2bf(v.z); o.w = f2bf(v.w);
        *(ushort4*)(dst + threadIdx.x * 4) = o;
        return;
    }
    float4 v = *(const float4*)(src + off + threadIdx.x * 4);
    ushort4 o;
    o.x = f2bf(v.x); o.y = f2bf(v.y); o.z = f2bf(v.z); o.w = f2bf(v.w);
    *(ushort4*)(dst + off + threadIdx.x * 4) = o;
}

// ---------------------------------------------------------------------------
// prep_vt: transpose 64-wide V slice per head (self-attention path).
// ---------------------------------------------------------------------------
__global__ __launch_bounds__(256)
void prep_vt(const _Float16* __restrict__ src, int L, int stride,
             int hmul, int hadd, _Float16* __restrict__ Vt) {
    const int b = blockIdx.z, h = blockIdx.y, m0 = blockIdx.x * 64;
    const int tid = threadIdx.x;
    __shared__ _Float16 vt[64][72];
    for (int idx = tid; idx < 512; idx += 256) {
        int m = idx >> 3, c = idx & 7;
        half8 v = *(const half8*)(src + ((size_t)(b * L + m0 + m)) * stride
                                  + h * hmul + hadd + c * 8);
#pragma unroll
        for (int k = 0; k < 8; k++) vt[c * 8 + k][m] = v[k];
    }
    __syncthreads();
    for (int idx = tid; idx < 512; idx += 256) {
        int d = idx >> 3, c = idx & 7;
        *(half8*)(Vt + (((size_t)(b * NHH + h)) * 64 + d) * L + m0 + c * 8)
            = *(const half8*)&vt[d][c * 8];
    }
}

// ---------------------------------------------------------------------------
// Flash MFMA attention v7: R12 structure (128 q/block, grid 512, __expf)
// with XOR chunk-swizzled LDS, stride 64: chunk j of row r stored at slot
// j^(r&7). All accesses 16B/8B aligned (full-rate ds_read_b128) AND spans
// disjoint within 8-lane issue groups -> conflict-free. Fixes both the
// stride-72 conflicts (R8: 3.4e6) and the stride-76 misalignment (R12:
// b128 -> split b64, +24% dur).
// ---------------------------------------------------------------------------
__global__ __launch_bounds__(256)
void attn7(const _Float16* __restrict__ Q, int qstride, int qmul, int qadd,
           const _Float16* __restrict__ K, int kstride, int kmul, int kadd,
           const _Float16* __restrict__ Vt, int LV, int Lrows,
           ushort_t* __restrict__ out, int kvlen, int causal) {
    const int g = blockIdx.x;
    const int bh = (g & 7) * 16 + ((g >> 3) & 15);
    const int qb = g >> 7;
    const int b = bh >> 3, h = bh & 7;
    const int n0 = qb * 128;
    const int tid = threadIdx.x, lane = tid & 63, w = tid >> 6;
    const int quad = lane >> 4, l16 = lane & 15;
    const int qw = n0 + w * 32;

    __shared__ _Float16 Ks[64 * 64];
    __shared__ _Float16 Vs[64 * 64];
    __shared__ _Float16 Ps[4][32 * 64];
    _Float16* Pw = Ps[w];

    half8 bq[2][2];
#pragma unroll
    for (int s = 0; s < 2; s++)
#pragma unroll
        for (int c = 0; c < 2; c++)
            bq[s][c] = *(const half8*)(Q + ((size_t)(b * NN + qw + s * 16 + l16)) * qstride
                                       + h * qmul + qadd + c * 32 + quad * 8);

    f32x4 acc[2][4] = {};
    float mrun[2] = {-3e38f, -3e38f}, lrun[2] = {0.f, 0.f};

    const int srow = tid >> 3;
    const int scol = tid & 7;                       // chunk index 0..7
    const int ssw = (scol ^ (srow & 7)) * 8;        // swizzled chunk offset
    const int limit = causal ? (n0 + 128) : kvlen;

    half8 kr0, kr1, vr0, vr1;
    {
        size_t kb = ((size_t)(b * Lrows + srow)) * kstride + h * kmul + kadd + scol * 8;
        kr0 = *(const half8*)(K + kb);
        kr1 = *(const half8*)(K + kb + (size_t)32 * kstride);
        size_t vb = (((size_t)(b * NHH + h)) * 64 + srow) * (size_t)LV + scol * 8;
        vr0 = *(const half8*)(Vt + vb);
        vr1 = *(const half8*)(Vt + vb + (size_t)32 * LV);
    }

    const int fsw = l16 & 7;                        // frag-read row swizzle
    for (int key0 = 0; key0 < limit; key0 += 64) {
        __syncthreads();
        *(half8*)&Ks[srow * 64 + ssw] = kr0;        // (srow+32)&7 == srow&7
        *(half8*)&Ks[(srow + 32) * 64 + ssw] = kr1;
        *(half8*)&Vs[srow * 64 + ssw] = vr0;
        *(half8*)&Vs[(srow + 32) * 64 + ssw] = vr1;
        __syncthreads();
        int knext = key0 + 64;
        if (knext < limit) {
            size_t kb = ((size_t)(b * Lrows + knext + srow)) * kstride
                        + h * kmul + kadd + scol * 8;
            kr0 = *(const half8*)(K + kb);
            kr1 = *(const half8*)(K + kb + (size_t)32 * kstride);
            size_t vb = (((size_t)(b * NHH + h)) * 64 + srow) * (size_t)LV
                        + knext + scol * 8;
            vr0 = *(const half8*)(Vt + vb);
            vr1 = *(const half8*)(Vt + vb + (size_t)32 * LV);
        }
        if (causal && key0 > qw + 31) continue;

        f32x4 st[2][4];
#pragma unroll
        for (int kt = 0; kt < 4; kt++) {
            const int rk = kt * 16 + l16;
            half8 ak0 = *(const half8*)&Ks[rk * 64 + ((quad ^ fsw) * 8)];
            half8 ak1 = *(const half8*)&Ks[rk * 64 + (((quad + 4) ^ fsw) * 8)];
#pragma unroll
            for (int s = 0; s < 2; s++) {
                f32x4 z = {};
                z = __builtin_amdgcn_mfma_f32_16x16x32_f16(ak0, bq[s][0], z, 0, 0, 0);
                z = __builtin_amdgcn_mfma_f32_16x16x32_f16(ak1, bq[s][1], z, 0, 0, 0);
                st[s][kt] = z;
            }
        }
        if (causal && key0 + 64 > qw) {
#pragma unroll
            for (int s = 0; s < 2; s++) {
                int qabs = qw + s * 16 + l16;
#pragma unroll
                for (int kt = 0; kt < 4; kt++)
#pragma unroll
                    for (int r = 0; r < 4; r++)
                        if (key0 + kt * 16 + quad * 4 + r > qabs)
                            st[s][kt][r] = -3e38f;
            }
        }
#pragma unroll
        for (int s = 0; s < 2; s++) {
            float lm = -3e38f;
#pragma unroll
            for (int kt = 0; kt < 4; kt++)
                lm = fmaxf(lm, fmaxf(fmaxf(st[s][kt][0], st[s][kt][1]),
                                     fmaxf(st[s][kt][2], st[s][kt][3])));
            lm = fmaxf(lm, __shfl_xor(lm, 16));
            lm = fmaxf(lm, __shfl_xor(lm, 32));
            float mnew = fmaxf(mrun[s], lm);
            float corr = __expf((mrun[s] - mnew) * 0.125f);
            mrun[s] = mnew;
            float ls = 0.f;
            const int rp = s * 16 + l16;
#pragma unroll
            for (int kt = 0; kt < 4; kt++) {
                half4 ph;
#pragma unroll
                for (int r = 0; r < 4; r++) {
                    float p = __expf((st[s][kt][r] - mnew) * 0.125f);
                    ls += p;
                    ph[r] = (_Float16)p;
                }
                // P half4 write: chunk j = 2*kt + (quad>>1), intra (quad&1)*4
                int jc = 2 * kt + (quad >> 1);
                *(half4*)&Pw[rp * 64 + ((jc ^ fsw) * 8) + (quad & 1) * 4] = ph;
            }
            ls += __shfl_xor(ls, 16);
            ls += __shfl_xor(ls, 32);
            lrun[s] = lrun[s] * corr + ls;
            float cb0 = __shfl(corr, (lane & 48) | (quad * 4 + 0));
            float cb1 = __shfl(corr, (lane & 48) | (quad * 4 + 1));
            float cb2 = __shfl(corr, (lane & 48) | (quad * 4 + 2));
            float cb3 = __shfl(corr, (lane & 48) | (quad * 4 + 3));
#pragma unroll
            for (int dt = 0; dt < 4; dt++) {
                acc[s][dt][0] *= cb0; acc[s][dt][1] *= cb1;
                acc[s][dt][2] *= cb2; acc[s][dt][3] *= cb3;
            }
        }
        half8 ap[2][2];
#pragma unroll
        for (int s = 0; s < 2; s++) {
            const int rp = s * 16 + l16;
#pragma unroll
            for (int c = 0; c < 2; c++)
                ap[s][c] = *(const half8*)&Pw[rp * 64 + (((c * 4 + quad) ^ fsw) * 8)];
        }
#pragma unroll
        for (int dt = 0; dt < 4; dt++) {
            const int rv = dt * 16 + l16;
            half8 bv0 = *(const half8*)&Vs[rv * 64 + ((quad ^ fsw) * 8)];
            half8 bv1 = *(const half8*)&Vs[rv * 64 + (((quad + 4) ^ fsw) * 8)];
#pragma unroll
            for (int s = 0; s < 2; s++) {
                acc[s][dt] = __builtin_amdgcn_mfma_f32_16x16x32_f16(ap[s][0], bv0, acc[s][dt], 0, 0, 0);
                acc[s][dt] = __builtin_amdgcn_mfma_f32_16x16x32_f16(ap[s][1], bv1, acc[s][dt], 0, 0, 0);
            }
        }
    }
#pragma unroll
    for (int s = 0; s < 2; s++) {
        float invq = 1.f / lrun[s];
        float iv0 = __shfl(invq, (lane & 48) | (quad * 4 + 0));
        float iv1 = __shfl(invq, (lane & 48) | (quad * 4 + 1));
        float iv2 = __shfl(invq, (lane & 48) | (quad * 4 + 2));
        float iv3 = __shfl(invq, (lane & 48) | (quad * 4 + 3));
#pragma unroll
        for (int dt = 0; dt < 4; dt++) {
            size_t base = ((size_t)(b * NN + qw + s * 16 + quad * 4)) * 512
                          + h * 64 + dt * 16 + l16;
            out[base]           = f2bf(acc[s][dt][0] * iv0);
            out[base + 512]     = f2bf(acc[s][dt][1] * iv1);
            out[base + 1024]    = f2bf(acc[s][dt][2] * iv2);
            out[base + 1536]    = f2bf(acc[s][dt][3] * iv3);
        }
    }
}

// ---------------------------------------------------------------------------
// out = LayerNorm(sum_{s<nsplit} u[s] + res)*g + beta; optional bf16 copy.
// ---------------------------------------------------------------------------
__global__ __launch_bounds__(256)
void ln_residual(const float* __restrict__ u, int nsplit,
                 const float* __restrict__ res,
                 const float* __restrict__ g, const float* __restrict__ be,
                 float* __restrict__ out, ushort_t* __restrict__ outbf) {
    const int row = blockIdx.x, t = threadIdx.x;
    const float* rp = res + (size_t)row * HIDD;
    float z0 = rp[t];
    float z1 = rp[t + 256];
    for (int s = 0; s < nsplit; s++) {
        const float* up = u + (size_t)s * 4194304 + (size_t)row * HIDD;
        z0 += up[t];
        z1 += up[t + 256];
    }
    float sm = z0 + z1, s2 = z0 * z0 + z1 * z1;
#pragma unroll
    for (int off = 1; off < 64; off <<= 1) {
        sm += __shfl_xor(sm, off, 64);
        s2 += __shfl_xor(s2, off, 64);
    }
    __shared__ float ps[4], ps2[4];
    int w = t >> 6;
    if ((t & 63) == 0) { ps[w] = sm; ps2[w] = s2; }
    __syncthreads();
    sm = ps[0] + ps[1] + ps[2] + ps[3];
    s2 = ps2[0] + ps2[1] + ps2[2] + ps2[3];
    float mu = sm * (1.f / 512.f);
    float var = s2 * (1.f / 512.f) - mu * mu;
    float rstd = rsqrtf(var + 1e-5f);
    float y0 = (z0 - mu) * rstd * g[t] + be[t];
    float y1 = (z1 - mu) * rstd * g[t + 256] + be[t + 256];
    out[(size_t)row * HIDD + t]       = y0;
    out[(size_t)row * HIDD + t + 256] = y1;
    if (outbf) {
        outbf[(size_t)row * HIDD + t]       = f2bf(y0);
        outbf[(size_t)row * HIDD + t + 256] = f2bf(y1);
    }
}

// ---------------------------------------------------------------------------
extern "C" void kernel_launch(void* const* d_in, const int* in_sizes, int n_in,
                              void* d_out, int out_size, void* d_ws, size_t ws_size,
                              hipStream_t stream) {
    const float* tgt      = (const float*)d_in[0];
    const float* mem      = (const float*)d_in[1];
    const float* pep_sin  = (const float*)d_in[2];
    const float* pep_cos  = (const float*)d_in[3];
    const float* pk_sin   = (const float*)d_in[4];
    const float* pk_cos   = (const float*)d_in[5];
    const float* mmha_w   = (const float*)d_in[8];
    const float* mmha_b   = (const float*)d_in[9];
    const float* mmha_ow  = (const float*)d_in[10];
    const float* mmha_ob  = (const float*)d_in[11];
    const float* mmha_g   = (const float*)d_in[12];
    const float* mmha_be  = (const float*)d_in[13];
    const float* mha_qw   = (const float*)d_in[14];
    const float* mha_qb   = (const float*)d_in[15];
    const float* mha_kvw  = (const float*)d_in[16];
    const float* mha_kvb  = (const float*)d_in[17];
    const float* mha_ow   = (const float*)d_in[18];
    const float* mha_ob   = (const float*)d_in[19];
    const float* mha_g    = (const float*)d_in[20];
    const float* mha_be   = (const float*)d_in[21];
    const float* ffn_w1   = (const float*)d_in[22];
    const float* ffn_w2   = (const float*)d_in[23];
    const float* ffn_g    = (const float*)d_in[24];
    const float* ffn_be   = (const float*)d_in[25];

    float* ws = (float*)d_ws;
    float* utmp  = ws;                        //  4,194,304 f32
    float* tgt12 = ws + 4194304;              //  4,194,304 f32
    _Float16* hp = (_Float16*)(ws + 8388608); // half pool (offsets in halves)
    _Float16* qkvh  = hp;                     // 12,582,912 (B*N*1536)
    _Float16* Qrot  = hp + 12582912;          //  4,194,304
    _Float16* Vth   = hp + 16777216;          //  8,388,608 (self uses half)
    _Float16* Krot  = hp + 25165824;          //  8,388,608
    ushort_t* membf = (ushort_t*)(hp + 33554432); // 8,388,608 bf16
    ushort_t* Abf   = (ushort_t*)(hp + 41943040); // 4,194,304 bf16
    ushort_t* Wbf   = (ushort_t*)(hp + 46137344); // 4,194,304 bf16 weights
    ushort_t* w_mmha = Wbf;                   //   786,432
    ushort_t* w_mmow = Wbf + 786432;          //   262,144
    ushort_t* w_qw   = Wbf + 1048576;         //   262,144
    ushort_t* w_kvw  = Wbf + 1310720;         //   524,288
    ushort_t* w_mow  = Wbf + 1835008;         //   262,144
    ushort_t* w_f1   = Wbf + 2097152;         // 1,048,576
    ushort_t* w_f2   = Wbf + 3145728;         // 1,048,576
    ushort_t* hbf = (ushort_t*)qkvh;          // ffn hidden bf16 spans qkvh+Qrot
    float* out = (float*)d_out;
    (void)in_sizes; (void)n_in; (void)out_size; (void)ws_size;

    // 0. all fp32->bf16 converts in one launch
    cvt_all<<<16384, 256, 0, stream>>>(tgt, mem, mmha_w, mmha_ow, mha_qw,
                                       mha_kvw, mha_ow, ffn_w1, ffn_w2,
                                       Abf, membf, Wbf);
    // 1. qkv = tgt @ mmha_w.T + b  (8192x512x1536, f16 out)
    gemm_bf<<<dim3(12, 64), 256, 0, stream>>>(Abf, w_mmha, mmha_b, nullptr, nullptr, qkvh, 512, 1536, 0);
    // 2. self-attention (causal), 128 q/block, swizzled LDS
    prep_vt<<<dim3(8, NHH, BB), 256, 0, stream>>>(qkvh, NN, 1536, 192, 128, Vth);
    attn7<<<512, 256, 0, stream>>>(qkvh, 1536, 192, 0, qkvh, 1536, 192, 64,
                                   Vth, NN, NN, Abf, 0, 1);
    // 3. tgt1 = LN(x @ ow.T + ob + tgt)
    gemm_bf64<<<dim3(8, 64), 256, 0, stream>>>(Abf, w_mmow, mmha_ob, utmp, nullptr, nullptr, 512, 512, 0);
    ln_residual<<<8192, 256, 0, stream>>>(utmp, 1, tgt, mmha_g, mmha_be, tgt12, Abf);
    // 4. Qrot = rot(tgt1 @ qw.T + qb)
    gemm_q_rot<<<dim3(8, 64), 256, 0, stream>>>(Abf, w_qw, mha_qb, pep_sin, pep_cos, Qrot);
    // 5. kv GEMM with fused k-rotation + v-transpose epilogue
    gemm_kv<<<dim3(8, 128), 256, 0, stream>>>(membf, w_kvw, mha_kvb, pk_sin, pk_cos, Krot, Vth);
    // 6. cross-attention (960 valid keys), 128 q/block, swizzled LDS
    attn7<<<512, 256, 0, stream>>>(Qrot, 512, 64, 0, Krot, 512, 64, 0,
                                   Vth, MM, MM, Abf, MM - 64, 0);
    // 7. tgt2 = LN(x2 @ ow.T + ob + tgt1)
    gemm_bf64<<<dim3(8, 64), 256, 0, stream>>>(Abf, w_mow, mha_ob, utmp, nullptr, nullptr, 512, 512, 0);
    ln_residual<<<8192, 256, 0, stream>>>(utmp, 1, tgt12, mha_g, mha_be, tgt12, Abf);
    // 8. h = relu(tgt2 @ w1.T)     (8192x512x2048, bf16 out)
    gemm_bf<<<dim3(16, 64), 256, 0, stream>>>(Abf, w_f1, nullptr, nullptr, hbf, nullptr, 512, 2048, 1);
    // 9. h2 = h @ w2.T  (8192x2048x512) 128x64 tiles, full K, XCD-swizzled
    gemm_bf64<<<dim3(8, 64), 256, 0, stream>>>(hbf, w_f2, nullptr, utmp, nullptr, nullptr, 2048, 512, 0);
    // 10. out = LN(tgt2 + h2)
    ln_residual<<<8192, 256, 0, stream>>>(utmp, 1, tgt12, ffn_g, ffn_be, out, nullptr);
}